// Round 9
// baseline (322.892 us; speedup 1.0000x reference)
//
#include <hip/hip_runtime.h>
#include <math.h>
#include <stdint.h>

// Problem constants
#define BB 4
#define HH 64
#define WW2 64
#define DM 96
#define DN 192
#define KK 4
#define NN 16
#define RR 6
#define LL 4096
#define RN 38   // R + 2N

#define LOG2E 1.4426950408889634f
#define LN2   0.6931471805599453f

// Workspace layout (4-byte word units). Peak = 22,875,408 words = 91.5 MB.
#define OFF_WDB      0           // u32[768] packed Wd sign bits + float[768] sd at +768
#define OFF_WCS      4608        // u32[192*56] packed conv weights
#define OFF_WAUX     15360       // int[192*8] conv border corrections
#define OFF_WSC      16896       // float[192] conv scale
#define OFF_WBIB     17088       // u32[384*3] packed W_in sign bits (rows 0..191 xp-half, 192..383 z-half)
#define OFF_WOUTB    18240       // u32[96*6] packed W_out sign bits
#define OFF_WLBB     18816       // u32[152*6] packed Wl sign bits
#define OFF_XBP      19728       // u32[4*6*4356] conv input bit planes (dead after k_conv)
#define OFF_PXS      19728       // u32[16*24576] packed sign(xs) flat — overwrites XBP, live thru corr
#define OFF_PXIN     412944     // u32[16384*3] input x sign bits (bilin_in -> ln_out)
#define OFF_XP       462096     // float[3145728] xp (B,Dn,L), dead after k_conv
#define OFF_XCONV    3607824    // float[3145728] conv out (B,Dn,L), dead after bits+xpose
#define OFF_XCT      6753552    // float[3145728] xconv t-major (B,L,Dn), live thru scan_a
#define OFF_HEND     462096     // float[128*49152] chunk h-ends / h0 (over dead XP+XCONV)
#define OFF_YA       9899280    // float[12582912] per-direction y (B,K,L,Dn), scan_a -> ln_out
#define OFF_SSUM     22482192   // float[128*3072] chunk delta sums

#define PLANE 4356   // 66*66
#define NCH 128      // 4096 / CHUNK
#define CHUNK 32

__device__ __forceinline__ float softplusf(float v) {
  return fmaxf(v, 0.f) + LN2 * log2f(1.f + exp2f(-fabsf(v) * LOG2E));
}
__device__ __forceinline__ float siluf(float v) {
  return v / (1.f + expf(-v));
}
__device__ __forceinline__ float waveAllSum(float s) {
  #pragma unroll
  for (int off = 32; off; off >>= 1) s += __shfl_xor(s, off, 64);
  return s;
}

// ---------------- prep: pack all sign weights + zero conv-plane borders ----------------
__global__ __launch_bounds__(64) void k_prep(
    const float* __restrict__ W_in, const float* __restrict__ s_in,
    const float* __restrict__ W_out, const float* __restrict__ s_out,
    const float* __restrict__ Wl, const float* __restrict__ sl,
    const float* __restrict__ Wd, const float* __restrict__ sd,
    const float* __restrict__ convW, float* __restrict__ ws) {
  __shared__ float srow[1728];
  int r = blockIdx.x, lane = threadIdx.x;
  if (r < 384) {
    const float* row = W_in + r * DM;
    float s = 0.f;
    for (int c = lane; c < DM; c += 64) s += row[c];
    s = waveAllSum(s);
    float mean = s / (float)DM;
    if (lane < 3) {
      uint32_t wv = 0;
      #pragma unroll
      for (int i = 0; i < 32; ++i) wv |= (row[lane * 32 + i] - mean > 0.f ? 1u : 0u) << i;
      ((uint32_t*)(ws + OFF_WBIB))[r * 3 + lane] = wv;
    }
  } else if (r < 480) {
    int m = r - 384;
    const float* row = W_out + m * DN;
    float s = 0.f;
    for (int c = lane; c < DN; c += 64) s += row[c];
    s = waveAllSum(s);
    float mean = s / (float)DN;
    if (lane < 6) {
      uint32_t wv = 0;
      #pragma unroll
      for (int i = 0; i < 32; ++i) wv |= (row[lane * 32 + i] - mean > 0.f ? 1u : 0u) << i;
      ((uint32_t*)(ws + OFF_WOUTB))[m * 6 + lane] = wv;
    }
  } else if (r < 632) {
    int idx = r - 480;
    const float* row = Wl + idx * DN;
    float s = 0.f;
    for (int c = lane; c < DN; c += 64) s += row[c];
    s = waveAllSum(s);
    float mean = s / (float)DN;
    if (lane < 6) {
      uint32_t wv = 0;
      #pragma unroll
      for (int i = 0; i < 32; ++i) wv |= (row[lane * 32 + i] - mean > 0.f ? 1u : 0u) << i;
      ((uint32_t*)(ws + OFF_WLBB))[idx * 6 + lane] = wv;
    }
  } else if (r < 1400) {
    int idx = r - 632;
    const float* row = Wd + idx * RR;
    float s = (lane < RR) ? row[lane] : 0.f;
    s = waveAllSum(s);
    float mean = s / (float)RR;
    unsigned long long mb = __ballot((lane < RR) && (row[lane] - mean > 0.f));
    if (lane == 0) {
      ((uint32_t*)(ws + OFF_WDB))[idx] = (uint32_t)mb & 0x3Fu;
      (ws + OFF_WDB)[768 + idx] = sd[idx];
    }
  } else if (r < 1592) {
    int o = r - 1400;
    const float* row = convW + o * 1728;
    float s = 0.f;
    for (int j = lane; j < 1728; j += 64) {
      float v = row[j];
      srow[j] = v;
      s += fabsf(v);
    }
    s = waveAllSum(s);
    __syncthreads();
    float sc = s / 1728.f;
    uint32_t* wb = (uint32_t*)(ws + OFF_WCS);
    int* aux = (int*)(ws + OFF_WAUX);
    float* scf = ws + OFF_WSC;
    uint32_t word = 0;
    if (lane < 54) {
      int cw = lane / 9, tap = lane % 9;
      #pragma unroll
      for (int i = 0; i < 32; ++i)
        word |= (srow[(cw * 32 + i) * 9 + tap] > 0.f ? 1u : 0u) << i;
      wb[o * 56 + lane] = word;
    } else if (lane < 56) {
      wb[o * 56 + lane] = 0u;
    }
    int pc = (lane < 54) ? 2 * (int)__popc(word) - 32 : 0;
    int tapid = lane % 9;
    int wst = 0;
    #pragma unroll
    for (int cw = 0; cw < 6; ++cw) wst += __shfl(pc, cw * 9 + tapid, 64);
    int w_t[9];
    #pragma unroll
    for (int t9 = 0; t9 < 9; ++t9) w_t[t9] = __shfl(wst, t9, 64);
    if (lane == 0) {
      aux[o * 8 + 0] = w_t[0] + w_t[3] + w_t[6];
      aux[o * 8 + 1] = w_t[2] + w_t[5] + w_t[8];
      aux[o * 8 + 2] = w_t[0] + w_t[1] + w_t[2];
      aux[o * 8 + 3] = w_t[6] + w_t[7] + w_t[8];
      aux[o * 8 + 4] = w_t[0];
      aux[o * 8 + 5] = w_t[2];
      aux[o * 8 + 6] = w_t[6];
      aux[o * 8 + 7] = w_t[8];
      scf[o] = sc;
    }
  } else {
    // zero the border of one conv bit-plane (24 planes)
    int p = r - 1592;
    uint32_t* plane = (uint32_t*)(ws + OFF_XBP) + (size_t)p * PLANE;
    for (int i = lane; i < 66; i += 64) {
      plane[i] = 0u;
      plane[65 * 66 + i] = 0u;
    }
    for (int i = lane; i < 64; i += 64) {
      plane[(i + 1) * 66] = 0u;
      plane[(i + 1) * 66 + 65] = 0u;
    }
  }
}

// ---------------- input bilinear (xp half only) + input sign-bit store + conv bit-pack ----------------
__global__ __launch_bounds__(384) void k_bilin_in(
    const float* __restrict__ x, const float* __restrict__ b_in,
    const float* __restrict__ s_in, const float* __restrict__ move0,
    const float* __restrict__ ws, float* __restrict__ xp,
    uint32_t* __restrict__ pxin, uint32_t* __restrict__ xb) {
  __shared__ uint32_t spx[16 * 3];
  __shared__ float sxz[192 * 17];
  __shared__ float smv[DN];
  int p0 = blockIdx.x * 16;
  if (threadIdx.x < 48) {
    int pix = threadIdx.x / 3, wd = threadIdx.x % 3;
    const float* base = x + (size_t)(p0 + pix) * DM + wd * 32;
    uint32_t wv = 0;
    #pragma unroll
    for (int i = 0; i < 32; ++i) wv |= (base[i] > 0.f ? 1u : 0u) << i;
    spx[pix * 3 + wd] = wv;
  }
  if (threadIdx.x < DN) smv[threadIdx.x] = move0[threadIdx.x];
  __syncthreads();
  int half = threadIdx.x / 192;
  int o = threadIdx.x - half * 192;
  uint32_t w0, w1, w2;
  {
    const uint32_t* wb = (const uint32_t*)(ws + OFF_WBIB) + o * 3;
    w0 = wb[0]; w1 = wb[1]; w2 = wb[2];
  }
  float bias = b_in[o], sc = s_in[o];
  #pragma unroll
  for (int pp = 0; pp < 8; ++pp) {
    int pix = half * 8 + pp;
    int P = (int)__popc(spx[pix * 3 + 0] ^ w0) + (int)__popc(spx[pix * 3 + 1] ^ w1) +
            (int)__popc(spx[pix * 3 + 2] ^ w2);
    sxz[o * 17 + pix] = bias + sc * (float)(DM - 2 * P);
  }
  __syncthreads();
  int b = p0 >> 12, l0 = p0 & 4095;
  for (int f = threadIdx.x; f < DN * 16; f += 384) {
    int od = f >> 4, pix = f & 15;
    xp[((size_t)(b * DN + od)) * LL + l0 + pix] = sxz[od * 17 + pix];
  }
  if (threadIdx.x < 48) {
    int pix = threadIdx.x / 3, wd = threadIdx.x % 3;
    pxin[(size_t)(p0 + pix) * 3 + wd] = spx[pix * 3 + wd];
  }
  if (threadIdx.x < 96) {
    int pix = threadIdx.x / 6, cw = threadIdx.x % 6;
    uint32_t wv = 0;
    #pragma unroll
    for (int i = 0; i < 32; ++i) {
      int dch = cw * 32 + i;
      wv |= ((sxz[dch * 17 + pix] + smv[dch] > 0.f) ? 1u : 0u) << i;
    }
    int l = l0 + pix, h = l >> 6, w = l & 63;
    uint32_t* plane = xb + (size_t)(b * 6 + cw) * PLANE;
    plane[(h + 1) * 66 + 1 + w] = wv;
  }
}

// ---------------- XNOR-popcount binary 3x3 conv + RPReLU + residual + SiLU ----------------
// grid 1024: b(4) x stripe(16) x og(4) x ocg(4); each block does 12 output channels.
__global__ __launch_bounds__(256) void k_conv(
    const uint32_t* __restrict__ xb, const float* __restrict__ xc,
    const uint32_t* __restrict__ wbits, const int* __restrict__ aux,
    const float* __restrict__ scf, const float* __restrict__ conv_b,
    const float* __restrict__ rp_b0, const float* __restrict__ prelu_a,
    const float* __restrict__ rp_b1, float* __restrict__ xconv) {
  int ocg = blockIdx.x & 3;
  int og = (blockIdx.x >> 2) & 3;
  int stripe = (blockIdx.x >> 4) & 15;
  int b = blockIdx.x >> 8;
  int w = threadIdx.x & 63, r = threadIdx.x >> 6;
  int h = stripe * 4 + r;
  int obase = og * 48 + ocg * 12;

  __shared__ uint32_t swb[12 * 56];
  __shared__ int saux[12 * 8];
  __shared__ float sconst[12 * 4];
  for (int i = threadIdx.x; i < 12 * 56; i += 256) swb[i] = wbits[obase * 56 + i];
  for (int i = threadIdx.x; i < 12 * 8; i += 256) saux[i] = aux[obase * 8 + i];
  if (threadIdx.x < 12) {
    int o = obase + threadIdx.x;
    sconst[threadIdx.x * 4 + 0] = scf[o];
    sconst[threadIdx.x * 4 + 1] = conv_b[o] + rp_b0[o];
    sconst[threadIdx.x * 4 + 2] = prelu_a[o];
    sconst[threadIdx.x * 4 + 3] = rp_b1[o];
  }

  uint32_t xw[6][9];
  const uint32_t* xpb = xb + (size_t)b * 6 * PLANE;
  #pragma unroll
  for (int cw = 0; cw < 6; ++cw) {
    const uint32_t* plane = xpb + cw * PLANE + (h + 1) * 66 + (w + 1);
    #pragma unroll
    for (int dy = 0; dy < 3; ++dy) {
      #pragma unroll
      for (int dx = 0; dx < 3; ++dx)
        xw[cw][dy * 3 + dx] = plane[(dy - 1) * 66 + (dx - 1)];
    }
  }
  bool isL = (w == 0), isR = (w == 63);
  bool isT = (h == 0), isB = (h == 63);
  const float* xcp = xc + ((size_t)(b * DN + obase)) * LL + h * 64 + w;
  float* xop = xconv + ((size_t)(b * DN + obase)) * LL + h * 64 + w;
  __syncthreads();

  #pragma unroll 1
  for (int oc = 0; oc < 12; ++oc) {
    const uint32_t* wp = &swb[oc * 56];
    int P = 0;
    #pragma unroll
    for (int cw = 0; cw < 6; ++cw) {
      int pp = 0;
      #pragma unroll
      for (int t = 0; t < 9; ++t) pp += (int)__popc(wp[cw * 9 + t] ^ xw[cw][t]);
      P += pp;
    }
    int corr = isL ? saux[oc * 8 + 0] : (isR ? saux[oc * 8 + 1] : 0);
    if (isT) {
      corr += saux[oc * 8 + 2];
      if (isL) corr -= saux[oc * 8 + 4];
      if (isR) corr -= saux[oc * 8 + 5];
    }
    if (isB) {
      corr += saux[oc * 8 + 3];
      if (isL) corr -= saux[oc * 8 + 6];
      if (isR) corr -= saux[oc * 8 + 7];
    }
    float acc = sconst[oc * 4 + 0] * (float)(1728 - 2 * P + corr);
    float t = acc + sconst[oc * 4 + 1];
    t = (t >= 0.f) ? t : sconst[oc * 4 + 2] * t;
    t += sconst[oc * 4 + 3] + *xcp;
    *xop = siluf(t);
    xcp += LL; xop += LL;
  }
}

// ---------------- fused: pack sign bits (blocks 0..767) + transpose to t-major (768..1535) ----------------
__global__ __launch_bounds__(256) void k_bits_xpose(const float* __restrict__ xconv,
                                                    uint32_t* __restrict__ pxs,
                                                    float* __restrict__ xct) {
  __shared__ float tile[64][65];
  if (blockIdx.x < 768) {
    int bd = blockIdx.x;
    int b = bd / DN, dch = bd - b * DN;
    const float* img = xconv + (size_t)bd * LL;
    for (int i = threadIdx.x; i < LL; i += 256)
      tile[i >> 6][i & 63] = img[i];
    __syncthreads();
    int lane = threadIdx.x & 63;
    #pragma unroll
    for (int k = 0; k < 4; ++k) {
      size_t wbase = ((size_t)((b * KK + k) * DN + dch)) * 128;
      for (int j = threadIdx.x; j < LL; j += 256) {
        float v;
        if (k == 0)      v = tile[j >> 6][j & 63];
        else if (k == 1) v = tile[j & 63][j >> 6];
        else if (k == 2) { int t2 = 4095 - j; v = tile[t2 >> 6][t2 & 63]; }
        else             { int t2 = 4095 - j; v = tile[t2 & 63][t2 >> 6]; }
        unsigned long long m = __ballot(v > 0.f);
        if (lane == 0)       pxs[wbase + (j >> 5)] = (uint32_t)m;
        else if (lane == 32) pxs[wbase + (j >> 5)] = (uint32_t)(m >> 32);
      }
    }
  } else {
    int idx = blockIdx.x - 768;
    int ts = idx & 63;
    int rest = idx >> 6;       // 0..11
    int dg = rest % 3;
    int b = rest / 3;
    int d0 = dg * 64, t0 = ts * 64;
    for (int i = threadIdx.x; i < 4096; i += 256) {
      int dd = i >> 6, tt = i & 63;
      tile[dd][tt] = xconv[((size_t)(b * DN + d0 + dd)) * LL + t0 + tt];
    }
    __syncthreads();
    for (int i = threadIdx.x; i < 4096; i += 256) {
      int tt = i >> 6, dd = i & 63;
      xct[((size_t)(b * LL + t0 + tt)) * DN + d0 + dd] = tile[dd][tt];
    }
  }
}

// power ladder: a[n] = r^(n+1), 14 mults, depth 4
__device__ __forceinline__ void rpowers(float r, float* a) {
  float r2 = r * r, r3 = r2 * r, r4 = r2 * r2, r8 = r4 * r4;
  a[0] = r;       a[1] = r2;      a[2] = r3;      a[3] = r4;
  a[4] = r4 * r;  a[5] = r4 * r2; a[6] = r4 * r3; a[7] = r8;
  a[8] = r8 * r;  a[9] = r8 * r2; a[10] = r8 * r3; a[11] = r8 * r4;
  a[12] = r8 * a[4]; a[13] = r8 * a[5]; a[14] = r8 * a[6]; a[15] = r8 * r8;
}

// row step (in floats) per unit t, valid within any 8-aligned seg (no low-6-bit carry)
__device__ __forceinline__ int rowstep(int k) {
  return (k == 0) ? DN : (k == 1) ? 64 * DN : (k == 2) ? -DN : -64 * DN;
}

// ---------------- scan pass A: FULL scan (zero h0), writes y^A, h-ends, Ssum ----------------
// R8: 384-thread blocks, TWO chunks per block (half = tid/192) — occupancy experiment:
// tests whether the residency cap is per-workgroup (then waves/CU doubles) or per-wave.
// grid = 64 chunk-pairs x 16 bk. dv/rho tables restored in LDS (R7 recompute regressed).
__global__ __launch_bounds__(384) void k_scan_a(
    const float* __restrict__ xct, const uint32_t* __restrict__ pxs,
    const float* __restrict__ ws, const float* __restrict__ bl,
    const float* __restrict__ sl, const float* __restrict__ bd,
    const float* __restrict__ dt_bias, const float* __restrict__ A_logs,
    const float* __restrict__ Ds, float* __restrict__ yA,
    float* __restrict__ hend, float* __restrict__ Ssum) {
  int cpair = blockIdx.x & 63;
  int bk = blockIdx.x >> 6;
  int k = bk & 3, b = bk >> 2;
  int half = threadIdx.x / 192;
  int d = threadIdx.x - half * 192;
  int c = cpair * 2 + half;
  int t0 = c << 5;
  __shared__ uint32_t sdtm[2][CHUNK];
  __shared__ uint32_t spxr[2][CHUNK * 6];
  __shared__ uint32_t swl[RN * 6];
  __shared__ float sblv[RN], sslv[RN];
  __shared__ float4 sB4[2][CHUNK * 4];
  __shared__ float4 sC4[2][CHUNK * 4];
  __shared__ float sDV[2][7 * 192], sR[2][7 * 192];
  float* sBf = (float*)sB4[half];
  float* sCf = (float*)sC4[half];
  const uint32_t* ppx = pxs + (size_t)bk * 24576;
  spxr[half][d] = ppx[t0 * 6 + d];                 // 192 words = 32 rows x 6, per half
  for (int i = threadIdx.x; i < RN * 6; i += 384)
    swl[i] = ((const uint32_t*)(ws + OFF_WLBB))[k * RN * 6 + i];
  if (threadIdx.x < RN) {
    sblv[threadIdx.x] = bl[k * RN + threadIdx.x];
    sslv[threadIdx.x] = sl[k * RN + threadIdx.x];
  }
  __syncthreads();
  // dt sign masks via raw-reshape mapping f = t*6+r -> row f>>12, col f&4095
  if (d < CHUNK) {
    uint32_t m = 0;
    int fbase = (t0 + d) * 6;
    #pragma unroll
    for (int r = 0; r < 6; ++r) {
      int f = fbase + r;
      int o = f >> 12, l = f & 4095;
      const uint32_t* prow = ppx + l * 6;
      int P = 0;
      #pragma unroll
      for (int j = 0; j < 6; ++j) P += (int)__popc(prow[j] ^ swl[o * 6 + j]);
      float val = sblv[o] + sslv[o] * (float)(DN - 2 * P);
      m |= (val > 0.f ? 1u : 0u) << r;
    }
    sdtm[half][d] = m;
  }
  // B and C values: rows RR..RR+31 (per half)
  for (int i = d; i < CHUNK * 32; i += 192) {
    int t = i >> 5, nn = i & 31;
    int o = RR + nn;
    int P = 0;
    #pragma unroll
    for (int j = 0; j < 6; ++j) P += (int)__popc(spxr[half][t * 6 + j] ^ swl[o * 6 + j]);
    float val = sblv[o] + sslv[o] * (float)(DN - 2 * P);
    if (nn < 16) sBf[t * 16 + nn] = val;
    else         sCf[t * 16 + (nn - 16)] = val;
  }
  uint32_t w6 = ((const uint32_t*)(ws + OFF_WDB))[k * DN + d];
  float sdvv = (ws + OFF_WDB)[768 + k * DN + d];
  float biasd = bd[k * DN + d] + dt_bias[k * DN + d];
  float Dd = Ds[k * DN + d];
  #pragma unroll
  for (int pc = 0; pc < 7; ++pc) {
    float dv = softplusf(biasd + sdvv * (float)(RR - 2 * pc));
    sDV[half][pc * 192 + d] = dv;
    sR[half][pc * 192 + d] = exp2f(-dv * LOG2E);
  }
  float Araw[16];
  bool fok = true;
  {
    const float* ap = A_logs + (k * DN + d) * NN;
    #pragma unroll
    for (int n = 0; n < NN; ++n) {
      Araw[n] = -expf(ap[n]);
      fok = fok && (fabsf(Araw[n] + (float)(n + 1)) < 1e-3f);
    }
  }
  bool fastpath = (__ballot(fok) == ~0ull);
  float An[16];
  if (!fastpath) {
    #pragma unroll
    for (int n = 0; n < NN; ++n) An[n] = Araw[n] * LOG2E;
  }
  float h[16];
  #pragma unroll
  for (int n = 0; n < NN; ++n) h[n] = 0.f;
  float S = 0.f;
  int ubase = b * (LL * DN) + d;
  int ybase = bk * (LL * DN) + d;
  int rstep = rowstep(k);
  __syncthreads();
  #pragma unroll 1
  for (int seg = 0; seg < 4; ++seg) {
    int tb = t0 + seg * 8;
    int r0 = (k >= 2) ? (4095 - tb) : tb;
    if (k & 1) r0 = ((r0 & 63) << 6) | (r0 >> 6);
    int rbase = r0 * DN;
    float uu[8];
    #pragma unroll
    for (int i = 0; i < 8; ++i) uu[i] = xct[ubase + rbase + i * rstep];
    #pragma unroll
    for (int i = 0; i < 8; ++i) {
      int t = seg * 8 + i;
      float uv = uu[i];
      int pc = (int)__popc(sdtm[half][t] ^ w6);
      float dv = sDV[half][pc * 192 + d];
      S += dv;
      float du = dv * uv;
      float yv = Dd * uv;
      if (fastpath) {
        float rv = sR[half][pc * 192 + d];
        float a[16];
        rpowers(rv, a);
        #pragma unroll
        for (int g = 0; g < 4; ++g) {
          float4 bv = sB4[half][t * 4 + g];
          float4 cv = sC4[half][t * 4 + g];
          h[4 * g + 0] = a[4 * g + 0] * h[4 * g + 0] + du * bv.x;
          h[4 * g + 1] = a[4 * g + 1] * h[4 * g + 1] + du * bv.y;
          h[4 * g + 2] = a[4 * g + 2] * h[4 * g + 2] + du * bv.z;
          h[4 * g + 3] = a[4 * g + 3] * h[4 * g + 3] + du * bv.w;
          yv += cv.x * h[4 * g + 0];
          yv += cv.y * h[4 * g + 1];
          yv += cv.z * h[4 * g + 2];
          yv += cv.w * h[4 * g + 3];
        }
      } else {
        #pragma unroll
        for (int g = 0; g < 4; ++g) {
          float4 bv = sB4[half][t * 4 + g];
          float4 cv = sC4[half][t * 4 + g];
          float a0 = exp2f(dv * An[4 * g + 0]);
          float a1 = exp2f(dv * An[4 * g + 1]);
          float a2 = exp2f(dv * An[4 * g + 2]);
          float a3 = exp2f(dv * An[4 * g + 3]);
          h[4 * g + 0] = a0 * h[4 * g + 0] + du * bv.x;
          h[4 * g + 1] = a1 * h[4 * g + 1] + du * bv.y;
          h[4 * g + 2] = a2 * h[4 * g + 2] + du * bv.z;
          h[4 * g + 3] = a3 * h[4 * g + 3] + du * bv.w;
          yv += cv.x * h[4 * g + 0];
          yv += cv.y * h[4 * g + 1];
          yv += cv.z * h[4 * g + 2];
          yv += cv.w * h[4 * g + 3];
        }
      }
      yA[ybase + rbase + i * rstep] = yv;
    }
  }
  float* hp = hend + (size_t)c * 49152 + (size_t)(bk * DN + d) * 16;
  #pragma unroll
  for (int n = 0; n < NN; n += 4)
    *(float4*)(hp + n) = make_float4(h[n], h[n + 1], h[n + 2], h[n + 3]);
  Ssum[c * 3072 + bk * DN + d] = S;
}

// ---------------- scan pass B: inter-chunk prefix (in place: h-ends -> h0) ----------------
__global__ __launch_bounds__(256) void k_scan_b(
    const float* __restrict__ A_logs, const float* __restrict__ Ssum,
    float* __restrict__ hend) {
  int tid = blockIdx.x * 256 + threadIdx.x;
  int bkd = tid >> 4, n = tid & 15;
  int bk = bkd / DN, d = bkd - bk * DN;
  int k = bk & 3;
  float An2 = -expf(A_logs[(k * DN + d) * NN + n]) * LOG2E;
  float h = 0.f;
  float Sc = Ssum[bkd];
  float he = hend[tid];
  #pragma unroll 1
  for (int c = 0; c < NCH; ++c) {
    float Sn = 0.f, hn = 0.f;
    if (c < NCH - 1) {
      Sn = Ssum[(c + 1) * 3072 + bkd];
      hn = hend[(size_t)(c + 1) * 49152 + tid];
    }
    hend[(size_t)c * 49152 + tid] = h;
    h = exp2f(An2 * Sc) * h + he;
    Sc = Sn; he = hn;
  }
}

// ---------------- scan pass C: correction y += C_t . (exp(A*S_t) o h0), in place on yA ----------------
// R8: 384-thread blocks, two chunks per block (same pairing as scan_a).
// c==0 half computes a provably-zero correction (h0[chunk0]=0 after scan_b); store guarded.
__global__ __launch_bounds__(384) void k_scan_corr(
    float* __restrict__ yA, const uint32_t* __restrict__ pxs,
    const float* __restrict__ ws, const float* __restrict__ bl,
    const float* __restrict__ sl, const float* __restrict__ bd,
    const float* __restrict__ dt_bias, const float* __restrict__ A_logs,
    const float* __restrict__ h0buf) {
  int cpair = blockIdx.x & 63;
  int bk = blockIdx.x >> 6;
  int k = bk & 3;
  int half = threadIdx.x / 192;
  int d = threadIdx.x - half * 192;
  int c = cpair * 2 + half;
  int t0 = c << 5;
  __shared__ uint32_t sdtm[2][CHUNK];
  __shared__ uint32_t spxr[2][CHUNK * 6];
  __shared__ uint32_t swl[RN * 6];
  __shared__ float sblv[RN], sslv[RN];
  __shared__ float4 sC4[2][CHUNK * 4];
  __shared__ float sDV[2][7 * 192];
  float* sCf = (float*)sC4[half];
  const uint32_t* ppx = pxs + (size_t)bk * 24576;
  spxr[half][d] = ppx[t0 * 6 + d];
  for (int i = threadIdx.x; i < RN * 6; i += 384)
    swl[i] = ((const uint32_t*)(ws + OFF_WLBB))[k * RN * 6 + i];
  if (threadIdx.x < RN) {
    sblv[threadIdx.x] = bl[k * RN + threadIdx.x];
    sslv[threadIdx.x] = sl[k * RN + threadIdx.x];
  }
  __syncthreads();
  if (d < CHUNK) {
    uint32_t m = 0;
    int fbase = (t0 + d) * 6;
    #pragma unroll
    for (int r = 0; r < 6; ++r) {
      int f = fbase + r;
      int o = f >> 12, l = f & 4095;
      const uint32_t* prow = ppx + l * 6;
      int P = 0;
      #pragma unroll
      for (int j = 0; j < 6; ++j) P += (int)__popc(prow[j] ^ swl[o * 6 + j]);
      float val = sblv[o] + sslv[o] * (float)(DN - 2 * P);
      m |= (val > 0.f ? 1u : 0u) << r;
    }
    sdtm[half][d] = m;
  }
  // C values only: rows RR+16..RR+31 (per half)
  for (int i = d; i < CHUNK * 16; i += 192) {
    int t = i >> 4, n = i & 15;
    int o = RR + NN + n;
    int P = 0;
    #pragma unroll
    for (int j = 0; j < 6; ++j) P += (int)__popc(spxr[half][t * 6 + j] ^ swl[o * 6 + j]);
    sCf[t * 16 + n] = sblv[o] + sslv[o] * (float)(DN - 2 * P);
  }
  uint32_t w6 = ((const uint32_t*)(ws + OFF_WDB))[k * DN + d];
  float sdvv = (ws + OFF_WDB)[768 + k * DN + d];
  float biasd = bd[k * DN + d] + dt_bias[k * DN + d];
  #pragma unroll
  for (int pc = 0; pc < 7; ++pc)
    sDV[half][pc * 192 + d] = softplusf(biasd + sdvv * (float)(RR - 2 * pc));
  float Araw[16];
  bool fok = true;
  {
    const float* ap = A_logs + (k * DN + d) * NN;
    #pragma unroll
    for (int n = 0; n < NN; ++n) {
      Araw[n] = -expf(ap[n]);
      fok = fok && (fabsf(Araw[n] + (float)(n + 1)) < 1e-3f);
    }
  }
  bool fastpath = (__ballot(fok) == ~0ull);
  float An[16];
  if (!fastpath) {
    #pragma unroll
    for (int n = 0; n < NN; ++n) An[n] = Araw[n] * LOG2E;
  }
  float h0[16];
  {
    const float* hp = h0buf + (size_t)c * 49152 + (size_t)(bk * DN + d) * 16;
    #pragma unroll
    for (int n = 0; n < NN; n += 4) {
      float4 v = *(const float4*)(hp + n);
      h0[n] = v.x; h0[n + 1] = v.y; h0[n + 2] = v.z; h0[n + 3] = v.w;
    }
  }
  float S = 0.f;
  int ybase = bk * (LL * DN) + d;
  int rstep = rowstep(k);
  __syncthreads();
  #pragma unroll 1
  for (int seg = 0; seg < 4; ++seg) {
    int tb = t0 + seg * 8;
    int r0 = (k >= 2) ? (4095 - tb) : tb;
    if (k & 1) r0 = ((r0 & 63) << 6) | (r0 >> 6);
    int rbase = r0 * DN;
    float yy[8];
    #pragma unroll
    for (int i = 0; i < 8; ++i) yy[i] = yA[ybase + rbase + i * rstep];
    #pragma unroll
    for (int i = 0; i < 8; ++i) {
      int t = seg * 8 + i;
      int pc = (int)__popc(sdtm[half][t] ^ w6);
      S += sDV[half][pc * 192 + d];
      float yv = 0.f;
      if (fastpath) {
        float rho = exp2f(-S * LOG2E);
        float a[16];
        rpowers(rho, a);
        #pragma unroll
        for (int g = 0; g < 4; ++g) {
          float4 cv = sC4[half][t * 4 + g];
          yv += cv.x * (a[4 * g + 0] * h0[4 * g + 0]);
          yv += cv.y * (a[4 * g + 1] * h0[4 * g + 1]);
          yv += cv.z * (a[4 * g + 2] * h0[4 * g + 2]);
          yv += cv.w * (a[4 * g + 3] * h0[4 * g + 3]);
        }
      } else {
        #pragma unroll
        for (int g = 0; g < 4; ++g) {
          float4 cv = sC4[half][t * 4 + g];
          yv += cv.x * (exp2f(S * An[4 * g + 0]) * h0[4 * g + 0]);
          yv += cv.y * (exp2f(S * An[4 * g + 1]) * h0[4 * g + 1]);
          yv += cv.z * (exp2f(S * An[4 * g + 2]) * h0[4 * g + 2]);
          yv += cv.w * (exp2f(S * An[4 * g + 3]) * h0[4 * g + 3]);
        }
      }
      if (c != 0) yA[ybase + rbase + i * rstep] = yy[i] + yv;
    }
  }
}

// ---------------- same-row combine 4 dirs + LayerNorm + sign(z) gate + output bilinear ----------------
// grid 1024: 16 rows/block.
__global__ __launch_bounds__(256) void k_ln_out(
    const float* __restrict__ yA, const uint32_t* __restrict__ pxin,
    const float* __restrict__ b_in, const float* __restrict__ s_in,
    const float* __restrict__ ln_w, const float* __restrict__ ln_b,
    const float* __restrict__ ws, const float* __restrict__ b_out,
    const float* __restrict__ s_out, float* __restrict__ out) {
  __shared__ float ty[16 * 193];
  __shared__ float ps[256];
  __shared__ float smu[16], srs[16];
  __shared__ float slw[DN], slb[DN];
  __shared__ uint32_t ybits[16 * 6];
  __shared__ uint32_t swo[96 * 6];
  __shared__ float sb[96], ssc[96];
  __shared__ uint32_t szw[DN * 3];
  __shared__ float szb[DN], szs[DN];
  __shared__ uint32_t spxt[16 * 3];
  int b = blockIdx.x >> 8;
  int l0 = (blockIdx.x & 255) << 4;
  if (threadIdx.x < DN) {
    slw[threadIdx.x] = ln_w[threadIdx.x];
    slb[threadIdx.x] = ln_b[threadIdx.x];
    szb[threadIdx.x] = b_in[DN + threadIdx.x];
    szs[threadIdx.x] = s_in[DN + threadIdx.x];
  }
  for (int i = threadIdx.x; i < 96 * 6; i += 256) swo[i] = ((const uint32_t*)(ws + OFF_WOUTB))[i];
  for (int i = threadIdx.x; i < DN * 3; i += 256) szw[i] = ((const uint32_t*)(ws + OFF_WBIB))[DN * 3 + i];
  if (threadIdx.x < 96) {
    sb[threadIdx.x] = b_out[threadIdx.x];
    ssc[threadIdx.x] = s_out[threadIdx.x];
  }
  if (threadIdx.x < 48) spxt[threadIdx.x] = pxin[(size_t)(b * LL + l0) * 3 + threadIdx.x];
  // scan_a stored every direction's y at its SPATIAL row -> same-row sum over k.
  const float* y0 = yA + (size_t)(b * 4 + 0) * (LL * DN) + (size_t)l0 * DN;
  const float* y1 = yA + (size_t)(b * 4 + 1) * (LL * DN) + (size_t)l0 * DN;
  const float* y2 = yA + (size_t)(b * 4 + 2) * (LL * DN) + (size_t)l0 * DN;
  const float* y3 = yA + (size_t)(b * 4 + 3) * (LL * DN) + (size_t)l0 * DN;
  for (int i = threadIdx.x; i < 16 * DN; i += 256) {
    int lc = i / DN, dd = i - lc * DN;
    size_t off = (size_t)lc * DN + dd;
    ty[lc * 193 + dd] = y0[off] + y1[off] + y2[off] + y3[off];
  }
  __syncthreads();
  int lc = threadIdx.x & 15, part = threadIdx.x >> 4;   // 16 parts x 12 d each
  float s = 0.f;
  for (int d = part * 12; d < part * 12 + 12; ++d) s += ty[lc * 193 + d];
  ps[threadIdx.x] = s;
  __syncthreads();
  if (threadIdx.x < 16) {
    float m = 0.f;
    #pragma unroll
    for (int p = 0; p < 16; ++p) m += ps[p * 16 + threadIdx.x];
    smu[threadIdx.x] = m / (float)DN;
  }
  __syncthreads();
  float mu = smu[lc];
  float q = 0.f;
  for (int d = part * 12; d < part * 12 + 12; ++d) {
    float v = ty[lc * 193 + d] - mu; q += v * v;
  }
  ps[threadIdx.x] = q;
  __syncthreads();
  if (threadIdx.x < 16) {
    float vv = 0.f;
    #pragma unroll
    for (int p = 0; p < 16; ++p) vv += ps[p * 16 + threadIdx.x];
    srs[threadIdx.x] = rsqrtf(vv / (float)DN + 1e-5f);
  }
  __syncthreads();
  if (threadIdx.x < 16 * 6) {
    int lc2 = threadIdx.x / 6, wd = threadIdx.x % 6;
    float mu2 = smu[lc2], rs2 = srs[lc2];
    uint32_t px0 = spxt[lc2 * 3 + 0], px1 = spxt[lc2 * 3 + 1], px2 = spxt[lc2 * 3 + 2];
    uint32_t wv = 0;
    #pragma unroll
    for (int i = 0; i < 32; ++i) {
      int dd = wd * 32 + i;
      float lnv = (ty[lc2 * 193 + dd] - mu2) * rs2 * slw[dd] + slb[dd];
      // gate: only the SIGN of ln * silu(z) matters, and sign(silu(z)) == sign(z)
      int P = (int)__popc(px0 ^ szw[dd * 3 + 0]) + (int)__popc(px1 ^ szw[dd * 3 + 1]) +
              (int)__popc(px2 ^ szw[dd * 3 + 2]);
      float zv = szb[dd] + szs[dd] * (float)(DM - 2 * P);
      wv |= ((lnv * zv > 0.f) ? 1u : 0u) << i;
    }
    ybits[lc2 * 6 + wd] = wv;
  }
  __syncthreads();
  float* op = out + (size_t)(b * LL + l0) * DM;
  for (int oi = threadIdx.x; oi < 16 * DM; oi += 256) {
    int pr = oi / DM, m = oi % DM;
    int P = 0;
    #pragma unroll
    for (int j = 0; j < 6; ++j) P += (int)__popc(ybits[pr * 6 + j] ^ swo[m * 6 + j]);
    op[(size_t)pr * DM + m] = sb[m] + ssc[m] * (float)(DN - 2 * P);
  }
}

extern "C" void kernel_launch(void* const* d_in, const int* in_sizes, int n_in,
                              void* d_out, int out_size, void* d_ws, size_t ws_size,
                              hipStream_t stream) {
  const float* x       = (const float*)d_in[0];
  const float* W_in    = (const float*)d_in[1];
  const float* b_in    = (const float*)d_in[2];
  const float* s_in    = (const float*)d_in[3];
  const float* move0_b = (const float*)d_in[4];
  const float* conv_W  = (const float*)d_in[5];
  const float* conv_b  = (const float*)d_in[6];
  const float* rp_b0   = (const float*)d_in[7];
  const float* prelu_a = (const float*)d_in[8];
  const float* rp_b1   = (const float*)d_in[9];
  const float* Wl      = (const float*)d_in[10];
  const float* bl      = (const float*)d_in[11];
  const float* sl      = (const float*)d_in[12];
  const float* Wd      = (const float*)d_in[13];
  const float* bd      = (const float*)d_in[14];
  const float* sd      = (const float*)d_in[15];
  const float* dt_bias = (const float*)d_in[16];
  const float* A_logs  = (const float*)d_in[17];
  const float* Ds      = (const float*)d_in[18];
  const float* ln_w    = (const float*)d_in[19];
  const float* ln_b    = (const float*)d_in[20];
  const float* W_out   = (const float*)d_in[21];
  const float* b_out   = (const float*)d_in[22];
  const float* s_out   = (const float*)d_in[23];
  float* ws  = (float*)d_ws;
  float* out = (float*)d_out;

  hipLaunchKernelGGL(k_prep, dim3(1616), dim3(64), 0, stream,
                     W_in, s_in, W_out, s_out, Wl, sl, Wd, sd, conv_W, ws);
  hipLaunchKernelGGL(k_bilin_in, dim3(1024), dim3(384), 0, stream,
                     x, b_in, s_in, move0_b, ws, ws + OFF_XP,
                     (uint32_t*)(ws + OFF_PXIN), (uint32_t*)(ws + OFF_XBP));
  hipLaunchKernelGGL(k_conv, dim3(1024), dim3(256), 0, stream,
                     (const uint32_t*)(ws + OFF_XBP), ws + OFF_XP,
                     (const uint32_t*)(ws + OFF_WCS), (const int*)(ws + OFF_WAUX),
                     ws + OFF_WSC, conv_b, rp_b0, prelu_a, rp_b1,
                     ws + OFF_XCONV);
  hipLaunchKernelGGL(k_bits_xpose, dim3(1536), dim3(256), 0, stream,
                     ws + OFF_XCONV, (uint32_t*)(ws + OFF_PXS), ws + OFF_XCT);
  hipLaunchKernelGGL(k_scan_a, dim3(1024), dim3(384), 0, stream,
                     ws + OFF_XCT, (const uint32_t*)(ws + OFF_PXS), ws, bl, sl,
                     bd, dt_bias, A_logs, Ds, ws + OFF_YA, ws + OFF_HEND,
                     ws + OFF_SSUM);
  hipLaunchKernelGGL(k_scan_b, dim3(192), dim3(256), 0, stream,
                     A_logs, ws + OFF_SSUM, ws + OFF_HEND);
  hipLaunchKernelGGL(k_scan_corr, dim3(1024), dim3(384), 0, stream,
                     ws + OFF_YA, (const uint32_t*)(ws + OFF_PXS), ws, bl, sl,
                     bd, dt_bias, A_logs, ws + OFF_HEND);
  hipLaunchKernelGGL(k_ln_out, dim3(1024), dim3(256), 0, stream,
                     ws + OFF_YA, (const uint32_t*)(ws + OFF_PXIN), b_in, s_in,
                     ln_w, ln_b, ws, b_out, s_out, out);
}

// Round 10
// 307.487 us; speedup vs baseline: 1.0501x; 1.0501x over previous
//
#include <hip/hip_runtime.h>
#include <math.h>
#include <stdint.h>

// Problem constants
#define BB 4
#define HH 64
#define WW2 64
#define DM 96
#define DN 192
#define KK 4
#define NN 16
#define RR 6
#define LL 4096
#define RN 38   // R + 2N

#define LOG2E 1.4426950408889634f
#define LN2   0.6931471805599453f

// Workspace layout (4-byte word units). Peak = 22,875,408 words = 91.5 MB.
#define OFF_WDB      0           // u32[768] packed Wd sign bits + float[768] sd at +768
#define OFF_WCS      4608        // u32[192*56] packed conv weights
#define OFF_WAUX     15360       // int[192*8] conv border corrections
#define OFF_WSC      16896       // float[192] conv scale
#define OFF_WBIB     17088       // u32[384*3] packed W_in sign bits (rows 0..191 xp-half, 192..383 z-half)
#define OFF_WOUTB    18240       // u32[96*6] packed W_out sign bits
#define OFF_WLBB     18816       // u32[152*6] packed Wl sign bits
#define OFF_XBP      19728       // u32[4*6*4356] conv input bit planes (dead after k_conv)
#define OFF_PXS      19728       // u32[16*24576] packed sign(xs) flat — overwrites XBP, live thru corr
#define OFF_PXIN     412944     // u32[16384*3] input x sign bits (bilin_in -> ln_out)
#define OFF_XP       462096     // float[3145728] xp (B,Dn,L), dead after k_conv
#define OFF_XCONV    3607824    // float[3145728] conv out (B,Dn,L), dead after bits+xpose
#define OFF_XCT      6753552    // float[3145728] xconv t-major (B,L,Dn), live thru scan_a
#define OFF_HEND     462096     // float[128*49152] chunk h-ends / h0 (over dead XP+XCONV)
#define OFF_YA       9899280    // float[12582912] per-direction y (B,K,L,Dn), scan_a -> ln_out
#define OFF_SSUM     22482192   // float[128*3072] chunk delta sums

#define PLANE 4356   // 66*66
#define NCH 128      // 4096 / CHUNK
#define CHUNK 32

__device__ __forceinline__ float softplusf(float v) {
  return fmaxf(v, 0.f) + LN2 * log2f(1.f + exp2f(-fabsf(v) * LOG2E));
}
__device__ __forceinline__ float siluf(float v) {
  return v / (1.f + expf(-v));
}
__device__ __forceinline__ float waveAllSum(float s) {
  #pragma unroll
  for (int off = 32; off; off >>= 1) s += __shfl_xor(s, off, 64);
  return s;
}

// ---------------- prep: pack all sign weights + zero conv-plane borders ----------------
__global__ __launch_bounds__(64) void k_prep(
    const float* __restrict__ W_in, const float* __restrict__ s_in,
    const float* __restrict__ W_out, const float* __restrict__ s_out,
    const float* __restrict__ Wl, const float* __restrict__ sl,
    const float* __restrict__ Wd, const float* __restrict__ sd,
    const float* __restrict__ convW, float* __restrict__ ws) {
  __shared__ float srow[1728];
  int r = blockIdx.x, lane = threadIdx.x;
  if (r < 384) {
    const float* row = W_in + r * DM;
    float s = 0.f;
    for (int c = lane; c < DM; c += 64) s += row[c];
    s = waveAllSum(s);
    float mean = s / (float)DM;
    if (lane < 3) {
      uint32_t wv = 0;
      #pragma unroll
      for (int i = 0; i < 32; ++i) wv |= (row[lane * 32 + i] - mean > 0.f ? 1u : 0u) << i;
      ((uint32_t*)(ws + OFF_WBIB))[r * 3 + lane] = wv;
    }
  } else if (r < 480) {
    int m = r - 384;
    const float* row = W_out + m * DN;
    float s = 0.f;
    for (int c = lane; c < DN; c += 64) s += row[c];
    s = waveAllSum(s);
    float mean = s / (float)DN;
    if (lane < 6) {
      uint32_t wv = 0;
      #pragma unroll
      for (int i = 0; i < 32; ++i) wv |= (row[lane * 32 + i] - mean > 0.f ? 1u : 0u) << i;
      ((uint32_t*)(ws + OFF_WOUTB))[m * 6 + lane] = wv;
    }
  } else if (r < 632) {
    int idx = r - 480;
    const float* row = Wl + idx * DN;
    float s = 0.f;
    for (int c = lane; c < DN; c += 64) s += row[c];
    s = waveAllSum(s);
    float mean = s / (float)DN;
    if (lane < 6) {
      uint32_t wv = 0;
      #pragma unroll
      for (int i = 0; i < 32; ++i) wv |= (row[lane * 32 + i] - mean > 0.f ? 1u : 0u) << i;
      ((uint32_t*)(ws + OFF_WLBB))[idx * 6 + lane] = wv;
    }
  } else if (r < 1400) {
    int idx = r - 632;
    const float* row = Wd + idx * RR;
    float s = (lane < RR) ? row[lane] : 0.f;
    s = waveAllSum(s);
    float mean = s / (float)RR;
    unsigned long long mb = __ballot((lane < RR) && (row[lane] - mean > 0.f));
    if (lane == 0) {
      ((uint32_t*)(ws + OFF_WDB))[idx] = (uint32_t)mb & 0x3Fu;
      (ws + OFF_WDB)[768 + idx] = sd[idx];
    }
  } else if (r < 1592) {
    int o = r - 1400;
    const float* row = convW + o * 1728;
    float s = 0.f;
    for (int j = lane; j < 1728; j += 64) {
      float v = row[j];
      srow[j] = v;
      s += fabsf(v);
    }
    s = waveAllSum(s);
    __syncthreads();
    float sc = s / 1728.f;
    uint32_t* wb = (uint32_t*)(ws + OFF_WCS);
    int* aux = (int*)(ws + OFF_WAUX);
    float* scf = ws + OFF_WSC;
    uint32_t word = 0;
    if (lane < 54) {
      int cw = lane / 9, tap = lane % 9;
      #pragma unroll
      for (int i = 0; i < 32; ++i)
        word |= (srow[(cw * 32 + i) * 9 + tap] > 0.f ? 1u : 0u) << i;
      wb[o * 56 + lane] = word;
    } else if (lane < 56) {
      wb[o * 56 + lane] = 0u;
    }
    int pc = (lane < 54) ? 2 * (int)__popc(word) - 32 : 0;
    int tapid = lane % 9;
    int wst = 0;
    #pragma unroll
    for (int cw = 0; cw < 6; ++cw) wst += __shfl(pc, cw * 9 + tapid, 64);
    int w_t[9];
    #pragma unroll
    for (int t9 = 0; t9 < 9; ++t9) w_t[t9] = __shfl(wst, t9, 64);
    if (lane == 0) {
      aux[o * 8 + 0] = w_t[0] + w_t[3] + w_t[6];
      aux[o * 8 + 1] = w_t[2] + w_t[5] + w_t[8];
      aux[o * 8 + 2] = w_t[0] + w_t[1] + w_t[2];
      aux[o * 8 + 3] = w_t[6] + w_t[7] + w_t[8];
      aux[o * 8 + 4] = w_t[0];
      aux[o * 8 + 5] = w_t[2];
      aux[o * 8 + 6] = w_t[6];
      aux[o * 8 + 7] = w_t[8];
      scf[o] = sc;
    }
  } else {
    // zero the border of one conv bit-plane (24 planes)
    int p = r - 1592;
    uint32_t* plane = (uint32_t*)(ws + OFF_XBP) + (size_t)p * PLANE;
    for (int i = lane; i < 66; i += 64) {
      plane[i] = 0u;
      plane[65 * 66 + i] = 0u;
    }
    for (int i = lane; i < 64; i += 64) {
      plane[(i + 1) * 66] = 0u;
      plane[(i + 1) * 66 + 65] = 0u;
    }
  }
}

// ---------------- input bilinear (xp half only) + input sign-bit store + conv bit-pack ----------------
__global__ __launch_bounds__(384) void k_bilin_in(
    const float* __restrict__ x, const float* __restrict__ b_in,
    const float* __restrict__ s_in, const float* __restrict__ move0,
    const float* __restrict__ ws, float* __restrict__ xp,
    uint32_t* __restrict__ pxin, uint32_t* __restrict__ xb) {
  __shared__ uint32_t spx[16 * 3];
  __shared__ float sxz[192 * 17];
  __shared__ float smv[DN];
  int p0 = blockIdx.x * 16;
  if (threadIdx.x < 48) {
    int pix = threadIdx.x / 3, wd = threadIdx.x % 3;
    const float* base = x + (size_t)(p0 + pix) * DM + wd * 32;
    uint32_t wv = 0;
    #pragma unroll
    for (int i = 0; i < 32; ++i) wv |= (base[i] > 0.f ? 1u : 0u) << i;
    spx[pix * 3 + wd] = wv;
  }
  if (threadIdx.x < DN) smv[threadIdx.x] = move0[threadIdx.x];
  __syncthreads();
  int half = threadIdx.x / 192;
  int o = threadIdx.x - half * 192;
  uint32_t w0, w1, w2;
  {
    const uint32_t* wb = (const uint32_t*)(ws + OFF_WBIB) + o * 3;
    w0 = wb[0]; w1 = wb[1]; w2 = wb[2];
  }
  float bias = b_in[o], sc = s_in[o];
  #pragma unroll
  for (int pp = 0; pp < 8; ++pp) {
    int pix = half * 8 + pp;
    int P = (int)__popc(spx[pix * 3 + 0] ^ w0) + (int)__popc(spx[pix * 3 + 1] ^ w1) +
            (int)__popc(spx[pix * 3 + 2] ^ w2);
    sxz[o * 17 + pix] = bias + sc * (float)(DM - 2 * P);
  }
  __syncthreads();
  int b = p0 >> 12, l0 = p0 & 4095;
  for (int f = threadIdx.x; f < DN * 16; f += 384) {
    int od = f >> 4, pix = f & 15;
    xp[((size_t)(b * DN + od)) * LL + l0 + pix] = sxz[od * 17 + pix];
  }
  if (threadIdx.x < 48) {
    int pix = threadIdx.x / 3, wd = threadIdx.x % 3;
    pxin[(size_t)(p0 + pix) * 3 + wd] = spx[pix * 3 + wd];
  }
  if (threadIdx.x < 96) {
    int pix = threadIdx.x / 6, cw = threadIdx.x % 6;
    uint32_t wv = 0;
    #pragma unroll
    for (int i = 0; i < 32; ++i) {
      int dch = cw * 32 + i;
      wv |= ((sxz[dch * 17 + pix] + smv[dch] > 0.f) ? 1u : 0u) << i;
    }
    int l = l0 + pix, h = l >> 6, w = l & 63;
    uint32_t* plane = xb + (size_t)(b * 6 + cw) * PLANE;
    plane[(h + 1) * 66 + 1 + w] = wv;
  }
}

// ---------------- XNOR-popcount binary 3x3 conv + RPReLU + residual + SiLU ----------------
// grid 1024: b(4) x stripe(16) x og(4) x ocg(4); each block does 12 output channels.
__global__ __launch_bounds__(256) void k_conv(
    const uint32_t* __restrict__ xb, const float* __restrict__ xc,
    const uint32_t* __restrict__ wbits, const int* __restrict__ aux,
    const float* __restrict__ scf, const float* __restrict__ conv_b,
    const float* __restrict__ rp_b0, const float* __restrict__ prelu_a,
    const float* __restrict__ rp_b1, float* __restrict__ xconv) {
  int ocg = blockIdx.x & 3;
  int og = (blockIdx.x >> 2) & 3;
  int stripe = (blockIdx.x >> 4) & 15;
  int b = blockIdx.x >> 8;
  int w = threadIdx.x & 63, r = threadIdx.x >> 6;
  int h = stripe * 4 + r;
  int obase = og * 48 + ocg * 12;

  __shared__ uint32_t swb[12 * 56];
  __shared__ int saux[12 * 8];
  __shared__ float sconst[12 * 4];
  for (int i = threadIdx.x; i < 12 * 56; i += 256) swb[i] = wbits[obase * 56 + i];
  for (int i = threadIdx.x; i < 12 * 8; i += 256) saux[i] = aux[obase * 8 + i];
  if (threadIdx.x < 12) {
    int o = obase + threadIdx.x;
    sconst[threadIdx.x * 4 + 0] = scf[o];
    sconst[threadIdx.x * 4 + 1] = conv_b[o] + rp_b0[o];
    sconst[threadIdx.x * 4 + 2] = prelu_a[o];
    sconst[threadIdx.x * 4 + 3] = rp_b1[o];
  }

  uint32_t xw[6][9];
  const uint32_t* xpb = xb + (size_t)b * 6 * PLANE;
  #pragma unroll
  for (int cw = 0; cw < 6; ++cw) {
    const uint32_t* plane = xpb + cw * PLANE + (h + 1) * 66 + (w + 1);
    #pragma unroll
    for (int dy = 0; dy < 3; ++dy) {
      #pragma unroll
      for (int dx = 0; dx < 3; ++dx)
        xw[cw][dy * 3 + dx] = plane[(dy - 1) * 66 + (dx - 1)];
    }
  }
  bool isL = (w == 0), isR = (w == 63);
  bool isT = (h == 0), isB = (h == 63);
  const float* xcp = xc + ((size_t)(b * DN + obase)) * LL + h * 64 + w;
  float* xop = xconv + ((size_t)(b * DN + obase)) * LL + h * 64 + w;
  __syncthreads();

  #pragma unroll 1
  for (int oc = 0; oc < 12; ++oc) {
    const uint32_t* wp = &swb[oc * 56];
    int P = 0;
    #pragma unroll
    for (int cw = 0; cw < 6; ++cw) {
      int pp = 0;
      #pragma unroll
      for (int t = 0; t < 9; ++t) pp += (int)__popc(wp[cw * 9 + t] ^ xw[cw][t]);
      P += pp;
    }
    int corr = isL ? saux[oc * 8 + 0] : (isR ? saux[oc * 8 + 1] : 0);
    if (isT) {
      corr += saux[oc * 8 + 2];
      if (isL) corr -= saux[oc * 8 + 4];
      if (isR) corr -= saux[oc * 8 + 5];
    }
    if (isB) {
      corr += saux[oc * 8 + 3];
      if (isL) corr -= saux[oc * 8 + 6];
      if (isR) corr -= saux[oc * 8 + 7];
    }
    float acc = sconst[oc * 4 + 0] * (float)(1728 - 2 * P + corr);
    float t = acc + sconst[oc * 4 + 1];
    t = (t >= 0.f) ? t : sconst[oc * 4 + 2] * t;
    t += sconst[oc * 4 + 3] + *xcp;
    *xop = siluf(t);
    xcp += LL; xop += LL;
  }
}

// ---------------- fused: pack sign bits (blocks 0..767) + transpose to t-major (768..1535) ----------------
__global__ __launch_bounds__(256) void k_bits_xpose(const float* __restrict__ xconv,
                                                    uint32_t* __restrict__ pxs,
                                                    float* __restrict__ xct) {
  __shared__ float tile[64][65];
  if (blockIdx.x < 768) {
    int bd = blockIdx.x;
    int b = bd / DN, dch = bd - b * DN;
    const float* img = xconv + (size_t)bd * LL;
    for (int i = threadIdx.x; i < LL; i += 256)
      tile[i >> 6][i & 63] = img[i];
    __syncthreads();
    int lane = threadIdx.x & 63;
    #pragma unroll
    for (int k = 0; k < 4; ++k) {
      size_t wbase = ((size_t)((b * KK + k) * DN + dch)) * 128;
      for (int j = threadIdx.x; j < LL; j += 256) {
        float v;
        if (k == 0)      v = tile[j >> 6][j & 63];
        else if (k == 1) v = tile[j & 63][j >> 6];
        else if (k == 2) { int t2 = 4095 - j; v = tile[t2 >> 6][t2 & 63]; }
        else             { int t2 = 4095 - j; v = tile[t2 & 63][t2 >> 6]; }
        unsigned long long m = __ballot(v > 0.f);
        if (lane == 0)       pxs[wbase + (j >> 5)] = (uint32_t)m;
        else if (lane == 32) pxs[wbase + (j >> 5)] = (uint32_t)(m >> 32);
      }
    }
  } else {
    int idx = blockIdx.x - 768;
    int ts = idx & 63;
    int rest = idx >> 6;       // 0..11
    int dg = rest % 3;
    int b = rest / 3;
    int d0 = dg * 64, t0 = ts * 64;
    for (int i = threadIdx.x; i < 4096; i += 256) {
      int dd = i >> 6, tt = i & 63;
      tile[dd][tt] = xconv[((size_t)(b * DN + d0 + dd)) * LL + t0 + tt];
    }
    __syncthreads();
    for (int i = threadIdx.x; i < 4096; i += 256) {
      int tt = i >> 6, dd = i & 63;
      xct[((size_t)(b * LL + t0 + tt)) * DN + d0 + dd] = tile[dd][tt];
    }
  }
}

// power ladder: a[n] = r^(n+1), 14 mults, depth 4
__device__ __forceinline__ void rpowers(float r, float* a) {
  float r2 = r * r, r3 = r2 * r, r4 = r2 * r2, r8 = r4 * r4;
  a[0] = r;       a[1] = r2;      a[2] = r3;      a[3] = r4;
  a[4] = r4 * r;  a[5] = r4 * r2; a[6] = r4 * r3; a[7] = r8;
  a[8] = r8 * r;  a[9] = r8 * r2; a[10] = r8 * r3; a[11] = r8 * r4;
  a[12] = r8 * a[4]; a[13] = r8 * a[5]; a[14] = r8 * a[6]; a[15] = r8 * r8;
}

// row step (in floats) per unit t, valid within any 8-aligned seg (no low-6-bit carry)
__device__ __forceinline__ int rowstep(int k) {
  return (k == 0) ? DN : (k == 1) ? 64 * DN : (k == 2) ? -DN : -64 * DN;
}
__device__ __forceinline__ int rowbase(int k, int tb) {
  int r0 = (k >= 2) ? (4095 - tb) : tb;
  if (k & 1) r0 = ((r0 & 63) << 6) | (r0 >> 6);
  return r0 * DN;
}

// ---------------- scan pass A: FULL scan (zero h0), writes y^A, h-ends, Ssum ----------------
// grid = 128 chunks x 16 bk; 192 threads (one per d). R10: software-prefetch the next
// seg's u-loads before computing the current seg (hides HBM/L2 latency under compute).
// Storing y at the SPATIAL row r(t) un-permutes all 4 directions (same-row sum in ln_out).
__global__ __launch_bounds__(192) void k_scan_a(
    const float* __restrict__ xct, const uint32_t* __restrict__ pxs,
    const float* __restrict__ ws, const float* __restrict__ bl,
    const float* __restrict__ sl, const float* __restrict__ bd,
    const float* __restrict__ dt_bias, const float* __restrict__ A_logs,
    const float* __restrict__ Ds, float* __restrict__ yA,
    float* __restrict__ hend, float* __restrict__ Ssum) {
  int c = blockIdx.x & (NCH - 1);
  int bk = blockIdx.x >> 7;
  int k = bk & 3, b = bk >> 2;
  int d = threadIdx.x;
  int t0 = c << 5;
  __shared__ uint32_t sdtm[CHUNK];
  __shared__ uint32_t spxr[CHUNK * 6];
  __shared__ uint32_t swl[RN * 6];
  __shared__ float sblv[RN], sslv[RN];
  __shared__ float4 sB4[CHUNK * 4];
  __shared__ float4 sC4[CHUNK * 4];
  __shared__ float sDV[7 * 192], sR[7 * 192];
  float* sBf = (float*)sB4;
  float* sCf = (float*)sC4;
  const uint32_t* ppx = pxs + (size_t)bk * 24576;
  spxr[d] = ppx[t0 * 6 + d];                       // 192 words = 32 rows x 6
  for (int i = d; i < RN * 6; i += 192) swl[i] = ((const uint32_t*)(ws + OFF_WLBB))[k * RN * 6 + i];
  if (d < RN) {
    sblv[d] = bl[k * RN + d];
    sslv[d] = sl[k * RN + d];
  }
  __syncthreads();
  // dt sign masks via raw-reshape mapping f = t*6+r -> row f>>12, col f&4095
  if (d < CHUNK) {
    uint32_t m = 0;
    int fbase = (t0 + d) * 6;
    #pragma unroll
    for (int r = 0; r < 6; ++r) {
      int f = fbase + r;
      int o = f >> 12, l = f & 4095;
      const uint32_t* prow = ppx + l * 6;
      int P = 0;
      #pragma unroll
      for (int j = 0; j < 6; ++j) P += (int)__popc(prow[j] ^ swl[o * 6 + j]);
      float val = sblv[o] + sslv[o] * (float)(DN - 2 * P);
      m |= (val > 0.f ? 1u : 0u) << r;
    }
    sdtm[d] = m;
  }
  // B and C values: rows RR..RR+31
  for (int i = d; i < CHUNK * 32; i += 192) {
    int t = i >> 5, nn = i & 31;
    int o = RR + nn;
    int P = 0;
    #pragma unroll
    for (int j = 0; j < 6; ++j) P += (int)__popc(spxr[t * 6 + j] ^ swl[o * 6 + j]);
    float val = sblv[o] + sslv[o] * (float)(DN - 2 * P);
    if (nn < 16) sBf[t * 16 + nn] = val;
    else         sCf[t * 16 + (nn - 16)] = val;
  }
  uint32_t w6 = ((const uint32_t*)(ws + OFF_WDB))[k * DN + d];
  float sdvv = (ws + OFF_WDB)[768 + k * DN + d];
  float biasd = bd[k * DN + d] + dt_bias[k * DN + d];
  float Dd = Ds[k * DN + d];
  #pragma unroll
  for (int pc = 0; pc < 7; ++pc) {
    float dv = softplusf(biasd + sdvv * (float)(RR - 2 * pc));
    sDV[pc * 192 + d] = dv;
    sR[pc * 192 + d] = exp2f(-dv * LOG2E);
  }
  float Araw[16];
  bool fok = true;
  {
    const float* ap = A_logs + (k * DN + d) * NN;
    #pragma unroll
    for (int n = 0; n < NN; ++n) {
      Araw[n] = -expf(ap[n]);
      fok = fok && (fabsf(Araw[n] + (float)(n + 1)) < 1e-3f);
    }
  }
  bool fastpath = (__ballot(fok) == ~0ull);
  float An[16];
  if (!fastpath) {
    #pragma unroll
    for (int n = 0; n < NN; ++n) An[n] = Araw[n] * LOG2E;
  }
  float h[16];
  #pragma unroll
  for (int n = 0; n < NN; ++n) h[n] = 0.f;
  float S = 0.f;
  int ubase = b * (LL * DN) + d;
  int ybase = bk * (LL * DN) + d;
  int rstep = rowstep(k);
  __syncthreads();
  // prefetch seg 0
  float uu[8], un[8];
  int rbase_cur = rowbase(k, t0);
  #pragma unroll
  for (int i = 0; i < 8; ++i) uu[i] = xct[ubase + rbase_cur + i * rstep];
  #pragma unroll 1
  for (int seg = 0; seg < 4; ++seg) {
    int rbase_next = 0;
    if (seg < 3) {
      rbase_next = rowbase(k, t0 + (seg + 1) * 8);
      #pragma unroll
      for (int i = 0; i < 8; ++i) un[i] = xct[ubase + rbase_next + i * rstep];
    }
    #pragma unroll
    for (int i = 0; i < 8; ++i) {
      int t = seg * 8 + i;
      float uv = uu[i];
      int pc = (int)__popc(sdtm[t] ^ w6);
      float dv = sDV[pc * 192 + d];
      S += dv;
      float du = dv * uv;
      float yv = Dd * uv;
      if (fastpath) {
        float rv = sR[pc * 192 + d];
        float a[16];
        rpowers(rv, a);
        #pragma unroll
        for (int g = 0; g < 4; ++g) {
          float4 bv = sB4[t * 4 + g];
          float4 cv = sC4[t * 4 + g];
          h[4 * g + 0] = a[4 * g + 0] * h[4 * g + 0] + du * bv.x;
          h[4 * g + 1] = a[4 * g + 1] * h[4 * g + 1] + du * bv.y;
          h[4 * g + 2] = a[4 * g + 2] * h[4 * g + 2] + du * bv.z;
          h[4 * g + 3] = a[4 * g + 3] * h[4 * g + 3] + du * bv.w;
          yv += cv.x * h[4 * g + 0];
          yv += cv.y * h[4 * g + 1];
          yv += cv.z * h[4 * g + 2];
          yv += cv.w * h[4 * g + 3];
        }
      } else {
        #pragma unroll
        for (int g = 0; g < 4; ++g) {
          float4 bv = sB4[t * 4 + g];
          float4 cv = sC4[t * 4 + g];
          float a0 = exp2f(dv * An[4 * g + 0]);
          float a1 = exp2f(dv * An[4 * g + 1]);
          float a2 = exp2f(dv * An[4 * g + 2]);
          float a3 = exp2f(dv * An[4 * g + 3]);
          h[4 * g + 0] = a0 * h[4 * g + 0] + du * bv.x;
          h[4 * g + 1] = a1 * h[4 * g + 1] + du * bv.y;
          h[4 * g + 2] = a2 * h[4 * g + 2] + du * bv.z;
          h[4 * g + 3] = a3 * h[4 * g + 3] + du * bv.w;
          yv += cv.x * h[4 * g + 0];
          yv += cv.y * h[4 * g + 1];
          yv += cv.z * h[4 * g + 2];
          yv += cv.w * h[4 * g + 3];
        }
      }
      yA[ybase + rbase_cur + i * rstep] = yv;
    }
    rbase_cur = rbase_next;
    #pragma unroll
    for (int i = 0; i < 8; ++i) uu[i] = un[i];
  }
  float* hp = hend + (size_t)c * 49152 + (size_t)(bk * DN + d) * 16;
  #pragma unroll
  for (int n = 0; n < NN; n += 4)
    *(float4*)(hp + n) = make_float4(h[n], h[n + 1], h[n + 2], h[n + 3]);
  Ssum[c * 3072 + bk * DN + d] = S;
}

// ---------------- scan pass B: inter-chunk prefix (in place: h-ends -> h0) ----------------
__global__ __launch_bounds__(256) void k_scan_b(
    const float* __restrict__ A_logs, const float* __restrict__ Ssum,
    float* __restrict__ hend) {
  int tid = blockIdx.x * 256 + threadIdx.x;
  int bkd = tid >> 4, n = tid & 15;
  int bk = bkd / DN, d = bkd - bk * DN;
  int k = bk & 3;
  float An2 = -expf(A_logs[(k * DN + d) * NN + n]) * LOG2E;
  float h = 0.f;
  float Sc = Ssum[bkd];
  float he = hend[tid];
  #pragma unroll 1
  for (int c = 0; c < NCH; ++c) {
    float Sn = 0.f, hn = 0.f;
    if (c < NCH - 1) {
      Sn = Ssum[(c + 1) * 3072 + bkd];
      hn = hend[(size_t)(c + 1) * 49152 + tid];
    }
    hend[(size_t)c * 49152 + tid] = h;
    h = exp2f(An2 * Sc) * h + he;
    Sc = Sn; he = hn;
  }
}

// ---------------- scan pass C: correction y += C_t . (exp(A*S_t) o h0), in place on yA ----------------
// R10: prefetch next seg's y-reads before current seg's compute (same pipelining as scan_a).
__global__ __launch_bounds__(192) void k_scan_corr(
    float* __restrict__ yA, const uint32_t* __restrict__ pxs,
    const float* __restrict__ ws, const float* __restrict__ bl,
    const float* __restrict__ sl, const float* __restrict__ bd,
    const float* __restrict__ dt_bias, const float* __restrict__ A_logs,
    const float* __restrict__ h0buf) {
  int c = blockIdx.x & (NCH - 1);
  if (c == 0) return;   // h0 == 0 for chunk 0, correction is zero
  int bk = blockIdx.x >> 7;
  int k = bk & 3;
  int d = threadIdx.x;
  int t0 = c << 5;
  __shared__ uint32_t sdtm[CHUNK];
  __shared__ uint32_t spxr[CHUNK * 6];
  __shared__ uint32_t swl[RN * 6];
  __shared__ float sblv[RN], sslv[RN];
  __shared__ float4 sC4[CHUNK * 4];
  __shared__ float sDV[7 * 192];
  float* sCf = (float*)sC4;
  const uint32_t* ppx = pxs + (size_t)bk * 24576;
  spxr[d] = ppx[t0 * 6 + d];
  for (int i = d; i < RN * 6; i += 192) swl[i] = ((const uint32_t*)(ws + OFF_WLBB))[k * RN * 6 + i];
  if (d < RN) {
    sblv[d] = bl[k * RN + d];
    sslv[d] = sl[k * RN + d];
  }
  __syncthreads();
  if (d < CHUNK) {
    uint32_t m = 0;
    int fbase = (t0 + d) * 6;
    #pragma unroll
    for (int r = 0; r < 6; ++r) {
      int f = fbase + r;
      int o = f >> 12, l = f & 4095;
      const uint32_t* prow = ppx + l * 6;
      int P = 0;
      #pragma unroll
      for (int j = 0; j < 6; ++j) P += (int)__popc(prow[j] ^ swl[o * 6 + j]);
      float val = sblv[o] + sslv[o] * (float)(DN - 2 * P);
      m |= (val > 0.f ? 1u : 0u) << r;
    }
    sdtm[d] = m;
  }
  // C values only: rows RR+16..RR+31
  for (int i = d; i < CHUNK * 16; i += 192) {
    int t = i >> 4, n = i & 15;
    int o = RR + NN + n;
    int P = 0;
    #pragma unroll
    for (int j = 0; j < 6; ++j) P += (int)__popc(spxr[t * 6 + j] ^ swl[o * 6 + j]);
    sCf[t * 16 + n] = sblv[o] + sslv[o] * (float)(DN - 2 * P);
  }
  uint32_t w6 = ((const uint32_t*)(ws + OFF_WDB))[k * DN + d];
  float sdvv = (ws + OFF_WDB)[768 + k * DN + d];
  float biasd = bd[k * DN + d] + dt_bias[k * DN + d];
  #pragma unroll
  for (int pc = 0; pc < 7; ++pc)
    sDV[pc * 192 + d] = softplusf(biasd + sdvv * (float)(RR - 2 * pc));
  float Araw[16];
  bool fok = true;
  {
    const float* ap = A_logs + (k * DN + d) * NN;
    #pragma unroll
    for (int n = 0; n < NN; ++n) {
      Araw[n] = -expf(ap[n]);
      fok = fok && (fabsf(Araw[n] + (float)(n + 1)) < 1e-3f);
    }
  }
  bool fastpath = (__ballot(fok) == ~0ull);
  float An[16];
  if (!fastpath) {
    #pragma unroll
    for (int n = 0; n < NN; ++n) An[n] = Araw[n] * LOG2E;
  }
  float h0[16];
  {
    const float* hp = h0buf + (size_t)c * 49152 + (size_t)(bk * DN + d) * 16;
    #pragma unroll
    for (int n = 0; n < NN; n += 4) {
      float4 v = *(const float4*)(hp + n);
      h0[n] = v.x; h0[n + 1] = v.y; h0[n + 2] = v.z; h0[n + 3] = v.w;
    }
  }
  float S = 0.f;
  int ybase = bk * (LL * DN) + d;
  int rstep = rowstep(k);
  __syncthreads();
  float yy[8], yn[8];
  int rbase_cur = rowbase(k, t0);
  #pragma unroll
  for (int i = 0; i < 8; ++i) yy[i] = yA[ybase + rbase_cur + i * rstep];
  #pragma unroll 1
  for (int seg = 0; seg < 4; ++seg) {
    int rbase_next = 0;
    if (seg < 3) {
      rbase_next = rowbase(k, t0 + (seg + 1) * 8);
      #pragma unroll
      for (int i = 0; i < 8; ++i) yn[i] = yA[ybase + rbase_next + i * rstep];
    }
    #pragma unroll
    for (int i = 0; i < 8; ++i) {
      int t = seg * 8 + i;
      int pc = (int)__popc(sdtm[t] ^ w6);
      S += sDV[pc * 192 + d];
      float yv = 0.f;
      if (fastpath) {
        float rho = exp2f(-S * LOG2E);
        float a[16];
        rpowers(rho, a);
        #pragma unroll
        for (int g = 0; g < 4; ++g) {
          float4 cv = sC4[t * 4 + g];
          yv += cv.x * (a[4 * g + 0] * h0[4 * g + 0]);
          yv += cv.y * (a[4 * g + 1] * h0[4 * g + 1]);
          yv += cv.z * (a[4 * g + 2] * h0[4 * g + 2]);
          yv += cv.w * (a[4 * g + 3] * h0[4 * g + 3]);
        }
      } else {
        #pragma unroll
        for (int g = 0; g < 4; ++g) {
          float4 cv = sC4[t * 4 + g];
          yv += cv.x * (exp2f(S * An[4 * g + 0]) * h0[4 * g + 0]);
          yv += cv.y * (exp2f(S * An[4 * g + 1]) * h0[4 * g + 1]);
          yv += cv.z * (exp2f(S * An[4 * g + 2]) * h0[4 * g + 2]);
          yv += cv.w * (exp2f(S * An[4 * g + 3]) * h0[4 * g + 3]);
        }
      }
      yA[ybase + rbase_cur + i * rstep] = yy[i] + yv;
    }
    rbase_cur = rbase_next;
    #pragma unroll
    for (int i = 0; i < 8; ++i) yy[i] = yn[i];
  }
}

// ---------------- same-row combine 4 dirs + LayerNorm + sign(z) gate + output bilinear ----------------
// grid 1024: 16 rows/block.
__global__ __launch_bounds__(256) void k_ln_out(
    const float* __restrict__ yA, const uint32_t* __restrict__ pxin,
    const float* __restrict__ b_in, const float* __restrict__ s_in,
    const float* __restrict__ ln_w, const float* __restrict__ ln_b,
    const float* __restrict__ ws, const float* __restrict__ b_out,
    const float* __restrict__ s_out, float* __restrict__ out) {
  __shared__ float ty[16 * 193];
  __shared__ float ps[256];
  __shared__ float smu[16], srs[16];
  __shared__ float slw[DN], slb[DN];
  __shared__ uint32_t ybits[16 * 6];
  __shared__ uint32_t swo[96 * 6];
  __shared__ float sb[96], ssc[96];
  __shared__ uint32_t szw[DN * 3];
  __shared__ float szb[DN], szs[DN];
  __shared__ uint32_t spxt[16 * 3];
  int b = blockIdx.x >> 8;
  int l0 = (blockIdx.x & 255) << 4;
  if (threadIdx.x < DN) {
    slw[threadIdx.x] = ln_w[threadIdx.x];
    slb[threadIdx.x] = ln_b[threadIdx.x];
    szb[threadIdx.x] = b_in[DN + threadIdx.x];
    szs[threadIdx.x] = s_in[DN + threadIdx.x];
  }
  for (int i = threadIdx.x; i < 96 * 6; i += 256) swo[i] = ((const uint32_t*)(ws + OFF_WOUTB))[i];
  for (int i = threadIdx.x; i < DN * 3; i += 256) szw[i] = ((const uint32_t*)(ws + OFF_WBIB))[DN * 3 + i];
  if (threadIdx.x < 96) {
    sb[threadIdx.x] = b_out[threadIdx.x];
    ssc[threadIdx.x] = s_out[threadIdx.x];
  }
  if (threadIdx.x < 48) spxt[threadIdx.x] = pxin[(size_t)(b * LL + l0) * 3 + threadIdx.x];
  // scan_a stored every direction's y at its SPATIAL row -> same-row sum over k.
  const float* y0 = yA + (size_t)(b * 4 + 0) * (LL * DN) + (size_t)l0 * DN;
  const float* y1 = yA + (size_t)(b * 4 + 1) * (LL * DN) + (size_t)l0 * DN;
  const float* y2 = yA + (size_t)(b * 4 + 2) * (LL * DN) + (size_t)l0 * DN;
  const float* y3 = yA + (size_t)(b * 4 + 3) * (LL * DN) + (size_t)l0 * DN;
  for (int i = threadIdx.x; i < 16 * DN; i += 256) {
    int lc = i / DN, dd = i - lc * DN;
    size_t off = (size_t)lc * DN + dd;
    ty[lc * 193 + dd] = y0[off] + y1[off] + y2[off] + y3[off];
  }
  __syncthreads();
  int lc = threadIdx.x & 15, part = threadIdx.x >> 4;   // 16 parts x 12 d each
  float s = 0.f;
  for (int d = part * 12; d < part * 12 + 12; ++d) s += ty[lc * 193 + d];
  ps[threadIdx.x] = s;
  __syncthreads();
  if (threadIdx.x < 16) {
    float m = 0.f;
    #pragma unroll
    for (int p = 0; p < 16; ++p) m += ps[p * 16 + threadIdx.x];
    smu[threadIdx.x] = m / (float)DN;
  }
  __syncthreads();
  float mu = smu[lc];
  float q = 0.f;
  for (int d = part * 12; d < part * 12 + 12; ++d) {
    float v = ty[lc * 193 + d] - mu; q += v * v;
  }
  ps[threadIdx.x] = q;
  __syncthreads();
  if (threadIdx.x < 16) {
    float vv = 0.f;
    #pragma unroll
    for (int p = 0; p < 16; ++p) vv += ps[p * 16 + threadIdx.x];
    srs[threadIdx.x] = rsqrtf(vv / (float)DN + 1e-5f);
  }
  __syncthreads();
  if (threadIdx.x < 16 * 6) {
    int lc2 = threadIdx.x / 6, wd = threadIdx.x % 6;
    float mu2 = smu[lc2], rs2 = srs[lc2];
    uint32_t px0 = spxt[lc2 * 3 + 0], px1 = spxt[lc2 * 3 + 1], px2 = spxt[lc2 * 3 + 2];
    uint32_t wv = 0;
    #pragma unroll
    for (int i = 0; i < 32; ++i) {
      int dd = wd * 32 + i;
      float lnv = (ty[lc2 * 193 + dd] - mu2) * rs2 * slw[dd] + slb[dd];
      // gate: only the SIGN of ln * silu(z) matters, and sign(silu(z)) == sign(z)
      int P = (int)__popc(px0 ^ szw[dd * 3 + 0]) + (int)__popc(px1 ^ szw[dd * 3 + 1]) +
              (int)__popc(px2 ^ szw[dd * 3 + 2]);
      float zv = szb[dd] + szs[dd] * (float)(DM - 2 * P);
      wv |= ((lnv * zv > 0.f) ? 1u : 0u) << i;
    }
    ybits[lc2 * 6 + wd] = wv;
  }
  __syncthreads();
  float* op = out + (size_t)(b * LL + l0) * DM;
  for (int oi = threadIdx.x; oi < 16 * DM; oi += 256) {
    int pr = oi / DM, m = oi % DM;
    int P = 0;
    #pragma unroll
    for (int j = 0; j < 6; ++j) P += (int)__popc(ybits[pr * 6 + j] ^ swo[m * 6 + j]);
    op[(size_t)pr * DM + m] = sb[m] + ssc[m] * (float)(DN - 2 * P);
  }
}

extern "C" void kernel_launch(void* const* d_in, const int* in_sizes, int n_in,
                              void* d_out, int out_size, void* d_ws, size_t ws_size,
                              hipStream_t stream) {
  const float* x       = (const float*)d_in[0];
  const float* W_in    = (const float*)d_in[1];
  const float* b_in    = (const float*)d_in[2];
  const float* s_in    = (const float*)d_in[3];
  const float* move0_b = (const float*)d_in[4];
  const float* conv_W  = (const float*)d_in[5];
  const float* conv_b  = (const float*)d_in[6];
  const float* rp_b0   = (const float*)d_in[7];
  const float* prelu_a = (const float*)d_in[8];
  const float* rp_b1   = (const float*)d_in[9];
  const float* Wl      = (const float*)d_in[10];
  const float* bl      = (const float*)d_in[11];
  const float* sl      = (const float*)d_in[12];
  const float* Wd      = (const float*)d_in[13];
  const float* bd      = (const float*)d_in[14];
  const float* sd      = (const float*)d_in[15];
  const float* dt_bias = (const float*)d_in[16];
  const float* A_logs  = (const float*)d_in[17];
  const float* Ds      = (const float*)d_in[18];
  const float* ln_w    = (const float*)d_in[19];
  const float* ln_b    = (const float*)d_in[20];
  const float* W_out   = (const float*)d_in[21];
  const float* b_out   = (const float*)d_in[22];
  const float* s_out   = (const float*)d_in[23];
  float* ws  = (float*)d_ws;
  float* out = (float*)d_out;

  hipLaunchKernelGGL(k_prep, dim3(1616), dim3(64), 0, stream,
                     W_in, s_in, W_out, s_out, Wl, sl, Wd, sd, conv_W, ws);
  hipLaunchKernelGGL(k_bilin_in, dim3(1024), dim3(384), 0, stream,
                     x, b_in, s_in, move0_b, ws, ws + OFF_XP,
                     (uint32_t*)(ws + OFF_PXIN), (uint32_t*)(ws + OFF_XBP));
  hipLaunchKernelGGL(k_conv, dim3(1024), dim3(256), 0, stream,
                     (const uint32_t*)(ws + OFF_XBP), ws + OFF_XP,
                     (const uint32_t*)(ws + OFF_WCS), (const int*)(ws + OFF_WAUX),
                     ws + OFF_WSC, conv_b, rp_b0, prelu_a, rp_b1,
                     ws + OFF_XCONV);
  hipLaunchKernelGGL(k_bits_xpose, dim3(1536), dim3(256), 0, stream,
                     ws + OFF_XCONV, (uint32_t*)(ws + OFF_PXS), ws + OFF_XCT);
  hipLaunchKernelGGL(k_scan_a, dim3(2048), dim3(192), 0, stream,
                     ws + OFF_XCT, (const uint32_t*)(ws + OFF_PXS), ws, bl, sl,
                     bd, dt_bias, A_logs, Ds, ws + OFF_YA, ws + OFF_HEND,
                     ws + OFF_SSUM);
  hipLaunchKernelGGL(k_scan_b, dim3(192), dim3(256), 0, stream,
                     A_logs, ws + OFF_SSUM, ws + OFF_HEND);
  hipLaunchKernelGGL(k_scan_corr, dim3(2048), dim3(192), 0, stream,
                     ws + OFF_YA, (const uint32_t*)(ws + OFF_PXS), ws, bl, sl,
                     bd, dt_bias, A_logs, ws + OFF_HEND);
  hipLaunchKernelGGL(k_ln_out, dim3(1024), dim3(256), 0, stream,
                     ws + OFF_YA, (const uint32_t*)(ws + OFF_PXIN), b_in, s_in,
                     ln_w, ln_b, ws, b_out, s_out, out);
}

// Round 12
// 300.347 us; speedup vs baseline: 1.0751x; 1.0238x over previous
//
#include <hip/hip_runtime.h>
#include <math.h>
#include <stdint.h>

// Problem constants
#define BB 4
#define HH 64
#define WW2 64
#define DM 96
#define DN 192
#define KK 4
#define NN 16
#define RR 6
#define LL 4096
#define RN 38   // R + 2N

#define LOG2E 1.4426950408889634f
#define LN2   0.6931471805599453f

// Workspace layout (4-byte word units). Peak = 22,875,408 words = 91.5 MB.
#define OFF_WDB      0           // u32[768] packed Wd sign bits + float[768] sd at +768
#define OFF_WCS      4608        // u32[192*56] packed conv weights
#define OFF_WAUX     15360       // int[192*8] conv border corrections
#define OFF_WSC      16896       // float[192] conv scale
#define OFF_WBIB     17088       // u32[384*3] packed W_in sign bits (rows 0..191 xp-half, 192..383 z-half)
#define OFF_WOUTB    18240       // u32[96*6] packed W_out sign bits
#define OFF_WLBB     18816       // u32[152*6] packed Wl sign bits
#define OFF_XBP      19728       // u32[4*6*4356] conv input bit planes (dead after k_conv)
#define OFF_PXS      19728       // u32[16*24576] packed sign(xs) flat — overwrites XBP, live thru scan_c
#define OFF_PXIN     412944     // u32[16384*3] input x sign bits (bilin_in -> ln_out)
#define OFF_XP       462096     // float[3145728] xp (B,Dn,L), dead after k_conv
#define OFF_XCONV    3607824    // float[3145728] conv out (B,Dn,L), dead after bits+xpose
#define OFF_XCT      6753552    // float[3145728] xconv t-major (B,L,Dn), live thru scan_c
#define OFF_HEND     462096     // float[128*49152] chunk h-ends / h0 (over dead XP+XCONV)
#define OFF_YA       9899280    // float[12582912] per-direction y (B,K,L,Dn), scan_c -> ln_out
#define OFF_SSUM     22482192   // float[128*3072] chunk delta sums

#define PLANE 4356   // 66*66
#define NCH 128      // 4096 / CHUNK
#define CHUNK 32

__device__ __forceinline__ float softplusf(float v) {
  return fmaxf(v, 0.f) + LN2 * log2f(1.f + exp2f(-fabsf(v) * LOG2E));
}
__device__ __forceinline__ float siluf(float v) {
  return v / (1.f + expf(-v));
}
__device__ __forceinline__ float waveAllSum(float s) {
  #pragma unroll
  for (int off = 32; off; off >>= 1) s += __shfl_xor(s, off, 64);
  return s;
}

// ---------------- prep: pack all sign weights + zero conv-plane borders ----------------
__global__ __launch_bounds__(64) void k_prep(
    const float* __restrict__ W_in, const float* __restrict__ s_in,
    const float* __restrict__ W_out, const float* __restrict__ s_out,
    const float* __restrict__ Wl, const float* __restrict__ sl,
    const float* __restrict__ Wd, const float* __restrict__ sd,
    const float* __restrict__ convW, float* __restrict__ ws) {
  __shared__ float srow[1728];
  int r = blockIdx.x, lane = threadIdx.x;
  if (r < 384) {
    const float* row = W_in + r * DM;
    float s = 0.f;
    for (int c = lane; c < DM; c += 64) s += row[c];
    s = waveAllSum(s);
    float mean = s / (float)DM;
    if (lane < 3) {
      uint32_t wv = 0;
      #pragma unroll
      for (int i = 0; i < 32; ++i) wv |= (row[lane * 32 + i] - mean > 0.f ? 1u : 0u) << i;
      ((uint32_t*)(ws + OFF_WBIB))[r * 3 + lane] = wv;
    }
  } else if (r < 480) {
    int m = r - 384;
    const float* row = W_out + m * DN;
    float s = 0.f;
    for (int c = lane; c < DN; c += 64) s += row[c];
    s = waveAllSum(s);
    float mean = s / (float)DN;
    if (lane < 6) {
      uint32_t wv = 0;
      #pragma unroll
      for (int i = 0; i < 32; ++i) wv |= (row[lane * 32 + i] - mean > 0.f ? 1u : 0u) << i;
      ((uint32_t*)(ws + OFF_WOUTB))[m * 6 + lane] = wv;
    }
  } else if (r < 632) {
    int idx = r - 480;
    const float* row = Wl + idx * DN;
    float s = 0.f;
    for (int c = lane; c < DN; c += 64) s += row[c];
    s = waveAllSum(s);
    float mean = s / (float)DN;
    if (lane < 6) {
      uint32_t wv = 0;
      #pragma unroll
      for (int i = 0; i < 32; ++i) wv |= (row[lane * 32 + i] - mean > 0.f ? 1u : 0u) << i;
      ((uint32_t*)(ws + OFF_WLBB))[idx * 6 + lane] = wv;
    }
  } else if (r < 1400) {
    int idx = r - 632;
    const float* row = Wd + idx * RR;
    float s = (lane < RR) ? row[lane] : 0.f;
    s = waveAllSum(s);
    float mean = s / (float)RR;
    unsigned long long mb = __ballot((lane < RR) && (row[lane] - mean > 0.f));
    if (lane == 0) {
      ((uint32_t*)(ws + OFF_WDB))[idx] = (uint32_t)mb & 0x3Fu;
      (ws + OFF_WDB)[768 + idx] = sd[idx];
    }
  } else if (r < 1592) {
    int o = r - 1400;
    const float* row = convW + o * 1728;
    float s = 0.f;
    for (int j = lane; j < 1728; j += 64) {
      float v = row[j];
      srow[j] = v;
      s += fabsf(v);
    }
    s = waveAllSum(s);
    __syncthreads();
    float sc = s / 1728.f;
    uint32_t* wb = (uint32_t*)(ws + OFF_WCS);
    int* aux = (int*)(ws + OFF_WAUX);
    float* scf = ws + OFF_WSC;
    uint32_t word = 0;
    if (lane < 54) {
      int cw = lane / 9, tap = lane % 9;
      #pragma unroll
      for (int i = 0; i < 32; ++i)
        word |= (srow[(cw * 32 + i) * 9 + tap] > 0.f ? 1u : 0u) << i;
      wb[o * 56 + lane] = word;
    } else if (lane < 56) {
      wb[o * 56 + lane] = 0u;
    }
    int pc = (lane < 54) ? 2 * (int)__popc(word) - 32 : 0;
    int tapid = lane % 9;
    int wst = 0;
    #pragma unroll
    for (int cw = 0; cw < 6; ++cw) wst += __shfl(pc, cw * 9 + tapid, 64);
    int w_t[9];
    #pragma unroll
    for (int t9 = 0; t9 < 9; ++t9) w_t[t9] = __shfl(wst, t9, 64);
    if (lane == 0) {
      aux[o * 8 + 0] = w_t[0] + w_t[3] + w_t[6];
      aux[o * 8 + 1] = w_t[2] + w_t[5] + w_t[8];
      aux[o * 8 + 2] = w_t[0] + w_t[1] + w_t[2];
      aux[o * 8 + 3] = w_t[6] + w_t[7] + w_t[8];
      aux[o * 8 + 4] = w_t[0];
      aux[o * 8 + 5] = w_t[2];
      aux[o * 8 + 6] = w_t[6];
      aux[o * 8 + 7] = w_t[8];
      scf[o] = sc;
    }
  } else {
    // zero the border of one conv bit-plane (24 planes)
    int p = r - 1592;
    uint32_t* plane = (uint32_t*)(ws + OFF_XBP) + (size_t)p * PLANE;
    for (int i = lane; i < 66; i += 64) {
      plane[i] = 0u;
      plane[65 * 66 + i] = 0u;
    }
    for (int i = lane; i < 64; i += 64) {
      plane[(i + 1) * 66] = 0u;
      plane[(i + 1) * 66 + 65] = 0u;
    }
  }
}

// ---------------- input bilinear (xp half only) + input sign-bit store + conv bit-pack ----------------
__global__ __launch_bounds__(384) void k_bilin_in(
    const float* __restrict__ x, const float* __restrict__ b_in,
    const float* __restrict__ s_in, const float* __restrict__ move0,
    const float* __restrict__ ws, float* __restrict__ xp,
    uint32_t* __restrict__ pxin, uint32_t* __restrict__ xb) {
  __shared__ uint32_t spx[16 * 3];
  __shared__ float sxz[192 * 17];
  __shared__ float smv[DN];
  int p0 = blockIdx.x * 16;
  if (threadIdx.x < 48) {
    int pix = threadIdx.x / 3, wd = threadIdx.x % 3;
    const float* base = x + (size_t)(p0 + pix) * DM + wd * 32;
    uint32_t wv = 0;
    #pragma unroll
    for (int i = 0; i < 32; ++i) wv |= (base[i] > 0.f ? 1u : 0u) << i;
    spx[pix * 3 + wd] = wv;
  }
  if (threadIdx.x < DN) smv[threadIdx.x] = move0[threadIdx.x];
  __syncthreads();
  int half = threadIdx.x / 192;
  int o = threadIdx.x - half * 192;
  uint32_t w0, w1, w2;
  {
    const uint32_t* wb = (const uint32_t*)(ws + OFF_WBIB) + o * 3;
    w0 = wb[0]; w1 = wb[1]; w2 = wb[2];
  }
  float bias = b_in[o], sc = s_in[o];
  #pragma unroll
  for (int pp = 0; pp < 8; ++pp) {
    int pix = half * 8 + pp;
    int P = (int)__popc(spx[pix * 3 + 0] ^ w0) + (int)__popc(spx[pix * 3 + 1] ^ w1) +
            (int)__popc(spx[pix * 3 + 2] ^ w2);
    sxz[o * 17 + pix] = bias + sc * (float)(DM - 2 * P);
  }
  __syncthreads();
  int b = p0 >> 12, l0 = p0 & 4095;
  for (int f = threadIdx.x; f < DN * 16; f += 384) {
    int od = f >> 4, pix = f & 15;
    xp[((size_t)(b * DN + od)) * LL + l0 + pix] = sxz[od * 17 + pix];
  }
  if (threadIdx.x < 48) {
    int pix = threadIdx.x / 3, wd = threadIdx.x % 3;
    pxin[(size_t)(p0 + pix) * 3 + wd] = spx[pix * 3 + wd];
  }
  if (threadIdx.x < 96) {
    int pix = threadIdx.x / 6, cw = threadIdx.x % 6;
    uint32_t wv = 0;
    #pragma unroll
    for (int i = 0; i < 32; ++i) {
      int dch = cw * 32 + i;
      wv |= ((sxz[dch * 17 + pix] + smv[dch] > 0.f) ? 1u : 0u) << i;
    }
    int l = l0 + pix, h = l >> 6, w = l & 63;
    uint32_t* plane = xb + (size_t)(b * 6 + cw) * PLANE;
    plane[(h + 1) * 66 + 1 + w] = wv;
  }
}

// ---------------- XNOR-popcount binary 3x3 conv + RPReLU + residual + SiLU ----------------
// grid 1024: b(4) x stripe(16) x og(4) x ocg(4); each block does 12 output channels.
__global__ __launch_bounds__(256) void k_conv(
    const uint32_t* __restrict__ xb, const float* __restrict__ xc,
    const uint32_t* __restrict__ wbits, const int* __restrict__ aux,
    const float* __restrict__ scf, const float* __restrict__ conv_b,
    const float* __restrict__ rp_b0, const float* __restrict__ prelu_a,
    const float* __restrict__ rp_b1, float* __restrict__ xconv) {
  int ocg = blockIdx.x & 3;
  int og = (blockIdx.x >> 2) & 3;
  int stripe = (blockIdx.x >> 4) & 15;
  int b = blockIdx.x >> 8;
  int w = threadIdx.x & 63, r = threadIdx.x >> 6;
  int h = stripe * 4 + r;
  int obase = og * 48 + ocg * 12;

  __shared__ uint32_t swb[12 * 56];
  __shared__ int saux[12 * 8];
  __shared__ float sconst[12 * 4];
  for (int i = threadIdx.x; i < 12 * 56; i += 256) swb[i] = wbits[obase * 56 + i];
  for (int i = threadIdx.x; i < 12 * 8; i += 256) saux[i] = aux[obase * 8 + i];
  if (threadIdx.x < 12) {
    int o = obase + threadIdx.x;
    sconst[threadIdx.x * 4 + 0] = scf[o];
    sconst[threadIdx.x * 4 + 1] = conv_b[o] + rp_b0[o];
    sconst[threadIdx.x * 4 + 2] = prelu_a[o];
    sconst[threadIdx.x * 4 + 3] = rp_b1[o];
  }

  uint32_t xw[6][9];
  const uint32_t* xpb = xb + (size_t)b * 6 * PLANE;
  #pragma unroll
  for (int cw = 0; cw < 6; ++cw) {
    const uint32_t* plane = xpb + cw * PLANE + (h + 1) * 66 + (w + 1);
    #pragma unroll
    for (int dy = 0; dy < 3; ++dy) {
      #pragma unroll
      for (int dx = 0; dx < 3; ++dx)
        xw[cw][dy * 3 + dx] = plane[(dy - 1) * 66 + (dx - 1)];
    }
  }
  bool isL = (w == 0), isR = (w == 63);
  bool isT = (h == 0), isB = (h == 63);
  const float* xcp = xc + ((size_t)(b * DN + obase)) * LL + h * 64 + w;
  float* xop = xconv + ((size_t)(b * DN + obase)) * LL + h * 64 + w;
  __syncthreads();

  #pragma unroll 1
  for (int oc = 0; oc < 12; ++oc) {
    const uint32_t* wp = &swb[oc * 56];
    int P = 0;
    #pragma unroll
    for (int cw = 0; cw < 6; ++cw) {
      int pp = 0;
      #pragma unroll
      for (int t = 0; t < 9; ++t) pp += (int)__popc(wp[cw * 9 + t] ^ xw[cw][t]);
      P += pp;
    }
    int corr = isL ? saux[oc * 8 + 0] : (isR ? saux[oc * 8 + 1] : 0);
    if (isT) {
      corr += saux[oc * 8 + 2];
      if (isL) corr -= saux[oc * 8 + 4];
      if (isR) corr -= saux[oc * 8 + 5];
    }
    if (isB) {
      corr += saux[oc * 8 + 3];
      if (isL) corr -= saux[oc * 8 + 6];
      if (isR) corr -= saux[oc * 8 + 7];
    }
    float acc = sconst[oc * 4 + 0] * (float)(1728 - 2 * P + corr);
    float t = acc + sconst[oc * 4 + 1];
    t = (t >= 0.f) ? t : sconst[oc * 4 + 2] * t;
    t += sconst[oc * 4 + 3] + *xcp;
    *xop = siluf(t);
    xcp += LL; xop += LL;
  }
}

// ---------------- fused: pack sign bits (blocks 0..767) + transpose to t-major (768..1535) ----------------
__global__ __launch_bounds__(256) void k_bits_xpose(const float* __restrict__ xconv,
                                                    uint32_t* __restrict__ pxs,
                                                    float* __restrict__ xct) {
  __shared__ float tile[64][65];
  if (blockIdx.x < 768) {
    int bd = blockIdx.x;
    int b = bd / DN, dch = bd - b * DN;
    const float* img = xconv + (size_t)bd * LL;
    for (int i = threadIdx.x; i < LL; i += 256)
      tile[i >> 6][i & 63] = img[i];
    __syncthreads();
    int lane = threadIdx.x & 63;
    #pragma unroll
    for (int k = 0; k < 4; ++k) {
      size_t wbase = ((size_t)((b * KK + k) * DN + dch)) * 128;
      for (int j = threadIdx.x; j < LL; j += 256) {
        float v;
        if (k == 0)      v = tile[j >> 6][j & 63];
        else if (k == 1) v = tile[j & 63][j >> 6];
        else if (k == 2) { int t2 = 4095 - j; v = tile[t2 >> 6][t2 & 63]; }
        else             { int t2 = 4095 - j; v = tile[t2 & 63][t2 >> 6]; }
        unsigned long long m = __ballot(v > 0.f);
        if (lane == 0)       pxs[wbase + (j >> 5)] = (uint32_t)m;
        else if (lane == 32) pxs[wbase + (j >> 5)] = (uint32_t)(m >> 32);
      }
    }
  } else {
    int idx = blockIdx.x - 768;
    int ts = idx & 63;
    int rest = idx >> 6;       // 0..11
    int dg = rest % 3;
    int b = rest / 3;
    int d0 = dg * 64, t0 = ts * 64;
    for (int i = threadIdx.x; i < 4096; i += 256) {
      int dd = i >> 6, tt = i & 63;
      tile[dd][tt] = xconv[((size_t)(b * DN + d0 + dd)) * LL + t0 + tt];
    }
    __syncthreads();
    for (int i = threadIdx.x; i < 4096; i += 256) {
      int tt = i >> 6, dd = i & 63;
      xct[((size_t)(b * LL + t0 + tt)) * DN + d0 + dd] = tile[dd][tt];
    }
  }
}

// power ladder: a[n] = r^(n+1), 14 mults, depth 4
__device__ __forceinline__ void rpowers(float r, float* a) {
  float r2 = r * r, r3 = r2 * r, r4 = r2 * r2, r8 = r4 * r4;
  a[0] = r;       a[1] = r2;      a[2] = r3;      a[3] = r4;
  a[4] = r4 * r;  a[5] = r4 * r2; a[6] = r4 * r3; a[7] = r8;
  a[8] = r8 * r;  a[9] = r8 * r2; a[10] = r8 * r3; a[11] = r8 * r4;
  a[12] = r8 * a[4]; a[13] = r8 * a[5]; a[14] = r8 * a[6]; a[15] = r8 * r8;
}

// row step (in floats) per unit t, valid within any 8-aligned seg (no low-6-bit carry)
__device__ __forceinline__ int rowstep(int k) {
  return (k == 0) ? DN : (k == 1) ? 64 * DN : (k == 2) ? -DN : -64 * DN;
}
__device__ __forceinline__ int rowbase(int k, int tb) {
  int r0 = (k >= 2) ? (4095 - tb) : tb;
  if (k & 1) r0 = ((r0 & 63) << 6) | (r0 >> 6);
  return r0 * DN;
}

// ---------------- scan pass A: recurrence ONLY -> h-ends + Ssum (no y, no C) ----------------
// R11 3-pass restructure: y production moved to pass C (single write, no RMW correction).
// grid = 128 chunks x 16 bk; 192 threads (one per d).
__global__ __launch_bounds__(192) void k_scan_a(
    const float* __restrict__ xct, const uint32_t* __restrict__ pxs,
    const float* __restrict__ ws, const float* __restrict__ bl,
    const float* __restrict__ sl, const float* __restrict__ bd,
    const float* __restrict__ dt_bias, const float* __restrict__ A_logs,
    float* __restrict__ hend, float* __restrict__ Ssum) {
  int c = blockIdx.x & (NCH - 1);
  int bk = blockIdx.x >> 7;
  int k = bk & 3, b = bk >> 2;
  int d = threadIdx.x;
  int t0 = c << 5;
  __shared__ uint32_t sdtm[CHUNK];
  __shared__ uint32_t spxr[CHUNK * 6];
  __shared__ uint32_t swl[RN * 6];
  __shared__ float sblv[RN], sslv[RN];
  __shared__ float4 sB4[CHUNK * 4];
  __shared__ float sDV[7 * 192], sR[7 * 192];
  float* sBf = (float*)sB4;
  const uint32_t* ppx = pxs + (size_t)bk * 24576;
  spxr[d] = ppx[t0 * 6 + d];                       // 192 words = 32 rows x 6
  for (int i = d; i < RN * 6; i += 192) swl[i] = ((const uint32_t*)(ws + OFF_WLBB))[k * RN * 6 + i];
  if (d < RN) {
    sblv[d] = bl[k * RN + d];
    sslv[d] = sl[k * RN + d];
  }
  __syncthreads();
  // dt sign masks via raw-reshape mapping f = t*6+r -> row f>>12, col f&4095
  if (d < CHUNK) {
    uint32_t m = 0;
    int fbase = (t0 + d) * 6;
    #pragma unroll
    for (int r = 0; r < 6; ++r) {
      int f = fbase + r;
      int o = f >> 12, l = f & 4095;
      const uint32_t* prow = ppx + l * 6;
      int P = 0;
      #pragma unroll
      for (int j = 0; j < 6; ++j) P += (int)__popc(prow[j] ^ swl[o * 6 + j]);
      float val = sblv[o] + sslv[o] * (float)(DN - 2 * P);
      m |= (val > 0.f ? 1u : 0u) << r;
    }
    sdtm[d] = m;
  }
  // B values only: rows RR..RR+15
  for (int i = d; i < CHUNK * 16; i += 192) {
    int t = i >> 4, n = i & 15;
    int o = RR + n;
    int P = 0;
    #pragma unroll
    for (int j = 0; j < 6; ++j) P += (int)__popc(spxr[t * 6 + j] ^ swl[o * 6 + j]);
    sBf[t * 16 + n] = sblv[o] + sslv[o] * (float)(DN - 2 * P);
  }
  uint32_t w6 = ((const uint32_t*)(ws + OFF_WDB))[k * DN + d];
  float sdvv = (ws + OFF_WDB)[768 + k * DN + d];
  float biasd = bd[k * DN + d] + dt_bias[k * DN + d];
  #pragma unroll
  for (int pc = 0; pc < 7; ++pc) {
    float dv = softplusf(biasd + sdvv * (float)(RR - 2 * pc));
    sDV[pc * 192 + d] = dv;
    sR[pc * 192 + d] = exp2f(-dv * LOG2E);
  }
  float Araw[16];
  bool fok = true;
  {
    const float* ap = A_logs + (k * DN + d) * NN;
    #pragma unroll
    for (int n = 0; n < NN; ++n) {
      Araw[n] = -expf(ap[n]);
      fok = fok && (fabsf(Araw[n] + (float)(n + 1)) < 1e-3f);
    }
  }
  bool fastpath = (__ballot(fok) == ~0ull);
  float An[16];
  if (!fastpath) {
    #pragma unroll
    for (int n = 0; n < NN; ++n) An[n] = Araw[n] * LOG2E;
  }
  float h[16];
  #pragma unroll
  for (int n = 0; n < NN; ++n) h[n] = 0.f;
  float S = 0.f;
  int ubase = b * (LL * DN) + d;
  int rstep = rowstep(k);
  __syncthreads();
  #pragma unroll 1
  for (int seg = 0; seg < 4; ++seg) {
    int rbase = rowbase(k, t0 + seg * 8);
    float uu[8];
    #pragma unroll
    for (int i = 0; i < 8; ++i) uu[i] = xct[ubase + rbase + i * rstep];
    #pragma unroll
    for (int i = 0; i < 8; ++i) {
      int t = seg * 8 + i;
      float uv = uu[i];
      int pc = (int)__popc(sdtm[t] ^ w6);
      float dv = sDV[pc * 192 + d];
      S += dv;
      float du = dv * uv;
      if (fastpath) {
        float rv = sR[pc * 192 + d];
        float a[16];
        rpowers(rv, a);
        #pragma unroll
        for (int g = 0; g < 4; ++g) {
          float4 bv = sB4[t * 4 + g];
          h[4 * g + 0] = a[4 * g + 0] * h[4 * g + 0] + du * bv.x;
          h[4 * g + 1] = a[4 * g + 1] * h[4 * g + 1] + du * bv.y;
          h[4 * g + 2] = a[4 * g + 2] * h[4 * g + 2] + du * bv.z;
          h[4 * g + 3] = a[4 * g + 3] * h[4 * g + 3] + du * bv.w;
        }
      } else {
        #pragma unroll
        for (int g = 0; g < 4; ++g) {
          float4 bv = sB4[t * 4 + g];
          float a0 = exp2f(dv * An[4 * g + 0]);
          float a1 = exp2f(dv * An[4 * g + 1]);
          float a2 = exp2f(dv * An[4 * g + 2]);
          float a3 = exp2f(dv * An[4 * g + 3]);
          h[4 * g + 0] = a0 * h[4 * g + 0] + du * bv.x;
          h[4 * g + 1] = a1 * h[4 * g + 1] + du * bv.y;
          h[4 * g + 2] = a2 * h[4 * g + 2] + du * bv.z;
          h[4 * g + 3] = a3 * h[4 * g + 3] + du * bv.w;
        }
      }
    }
  }
  float* hp = hend + (size_t)c * 49152 + (size_t)(bk * DN + d) * 16;
  #pragma unroll
  for (int n = 0; n < NN; n += 4)
    *(float4*)(hp + n) = make_float4(h[n], h[n + 1], h[n + 2], h[n + 3]);
  Ssum[c * 3072 + bk * DN + d] = S;
}

// ---------------- scan pass B: inter-chunk prefix (in place: h-ends -> h0) ----------------
__global__ __launch_bounds__(256) void k_scan_b(
    const float* __restrict__ A_logs, const float* __restrict__ Ssum,
    float* __restrict__ hend) {
  int tid = blockIdx.x * 256 + threadIdx.x;
  int bkd = tid >> 4, n = tid & 15;
  int bk = bkd / DN, d = bkd - bk * DN;
  int k = bk & 3;
  float An2 = -expf(A_logs[(k * DN + d) * NN + n]) * LOG2E;
  float h = 0.f;
  float Sc = Ssum[bkd];
  float he = hend[tid];
  #pragma unroll 1
  for (int c = 0; c < NCH; ++c) {
    float Sn = 0.f, hn = 0.f;
    if (c < NCH - 1) {
      Sn = Ssum[(c + 1) * 3072 + bkd];
      hn = hend[(size_t)(c + 1) * 49152 + tid];
    }
    hend[(size_t)c * 49152 + tid] = h;
    h = exp2f(An2 * Sc) * h + he;
    Sc = Sn; he = hn;
  }
}

// ---------------- scan pass C: FULL scan from h0, single y write (no RMW) ----------------
// h initialized from h0buf (hend after scan_b); yv via 4-partial tree (reassociation OK,
// tolerance 1e-2 vs observed 2e-7). Stores y at the SPATIAL row -> same-row sum in ln_out.
__global__ __launch_bounds__(192) void k_scan_c(
    const float* __restrict__ xct, const uint32_t* __restrict__ pxs,
    const float* __restrict__ ws, const float* __restrict__ bl,
    const float* __restrict__ sl, const float* __restrict__ bd,
    const float* __restrict__ dt_bias, const float* __restrict__ A_logs,
    const float* __restrict__ Ds, float* __restrict__ yA,
    const float* __restrict__ h0buf) {
  int c = blockIdx.x & (NCH - 1);
  int bk = blockIdx.x >> 7;
  int k = bk & 3, b = bk >> 2;
  int d = threadIdx.x;
  int t0 = c << 5;
  __shared__ uint32_t sdtm[CHUNK];
  __shared__ uint32_t spxr[CHUNK * 6];
  __shared__ uint32_t swl[RN * 6];
  __shared__ float sblv[RN], sslv[RN];
  __shared__ float4 sB4[CHUNK * 4];
  __shared__ float4 sC4[CHUNK * 4];
  __shared__ float sDV[7 * 192], sR[7 * 192];
  float* sBf = (float*)sB4;
  float* sCf = (float*)sC4;
  const uint32_t* ppx = pxs + (size_t)bk * 24576;
  spxr[d] = ppx[t0 * 6 + d];
  for (int i = d; i < RN * 6; i += 192) swl[i] = ((const uint32_t*)(ws + OFF_WLBB))[k * RN * 6 + i];
  if (d < RN) {
    sblv[d] = bl[k * RN + d];
    sslv[d] = sl[k * RN + d];
  }
  __syncthreads();
  if (d < CHUNK) {
    uint32_t m = 0;
    int fbase = (t0 + d) * 6;
    #pragma unroll
    for (int r = 0; r < 6; ++r) {
      int f = fbase + r;
      int o = f >> 12, l = f & 4095;
      const uint32_t* prow = ppx + l * 6;
      int P = 0;
      #pragma unroll
      for (int j = 0; j < 6; ++j) P += (int)__popc(prow[j] ^ swl[o * 6 + j]);
      float val = sblv[o] + sslv[o] * (float)(DN - 2 * P);
      m |= (val > 0.f ? 1u : 0u) << r;
    }
    sdtm[d] = m;
  }
  // B and C values: rows RR..RR+31
  for (int i = d; i < CHUNK * 32; i += 192) {
    int t = i >> 5, nn = i & 31;
    int o = RR + nn;
    int P = 0;
    #pragma unroll
    for (int j = 0; j < 6; ++j) P += (int)__popc(spxr[t * 6 + j] ^ swl[o * 6 + j]);
    float val = sblv[o] + sslv[o] * (float)(DN - 2 * P);
    if (nn < 16) sBf[t * 16 + nn] = val;
    else         sCf[t * 16 + (nn - 16)] = val;
  }
  uint32_t w6 = ((const uint32_t*)(ws + OFF_WDB))[k * DN + d];
  float sdvv = (ws + OFF_WDB)[768 + k * DN + d];
  float biasd = bd[k * DN + d] + dt_bias[k * DN + d];
  float Dd = Ds[k * DN + d];
  #pragma unroll
  for (int pc = 0; pc < 7; ++pc) {
    float dv = softplusf(biasd + sdvv * (float)(RR - 2 * pc));
    sDV[pc * 192 + d] = dv;
    sR[pc * 192 + d] = exp2f(-dv * LOG2E);
  }
  float Araw[16];
  bool fok = true;
  {
    const float* ap = A_logs + (k * DN + d) * NN;
    #pragma unroll
    for (int n = 0; n < NN; ++n) {
      Araw[n] = -expf(ap[n]);
      fok = fok && (fabsf(Araw[n] + (float)(n + 1)) < 1e-3f);
    }
  }
  bool fastpath = (__ballot(fok) == ~0ull);
  float An[16];
  if (!fastpath) {
    #pragma unroll
    for (int n = 0; n < NN; ++n) An[n] = Araw[n] * LOG2E;
  }
  // h0 from scan_b output (zeros for c==0)
  float h[16];
  {
    const float* hp = h0buf + (size_t)c * 49152 + (size_t)(bk * DN + d) * 16;
    #pragma unroll
    for (int n = 0; n < NN; n += 4) {
      float4 v = *(const float4*)(hp + n);
      h[n] = v.x; h[n + 1] = v.y; h[n + 2] = v.z; h[n + 3] = v.w;
    }
  }
  int ubase = b * (LL * DN) + d;
  int ybase = bk * (LL * DN) + d;
  int rstep = rowstep(k);
  __syncthreads();
  #pragma unroll 1
  for (int seg = 0; seg < 4; ++seg) {
    int rbase = rowbase(k, t0 + seg * 8);
    float uu[8];
    #pragma unroll
    for (int i = 0; i < 8; ++i) uu[i] = xct[ubase + rbase + i * rstep];
    #pragma unroll
    for (int i = 0; i < 8; ++i) {
      int t = seg * 8 + i;
      float uv = uu[i];
      int pc = (int)__popc(sdtm[t] ^ w6);
      float dv = sDV[pc * 192 + d];
      float du = dv * uv;
      float p[4];
      #pragma unroll
      for (int g = 0; g < 4; ++g) p[g] = 0.f;
      if (fastpath) {
        float rv = sR[pc * 192 + d];
        float a[16];
        rpowers(rv, a);
        #pragma unroll
        for (int g = 0; g < 4; ++g) {
          float4 bv = sB4[t * 4 + g];
          float4 cv = sC4[t * 4 + g];
          h[4 * g + 0] = a[4 * g + 0] * h[4 * g + 0] + du * bv.x;
          h[4 * g + 1] = a[4 * g + 1] * h[4 * g + 1] + du * bv.y;
          h[4 * g + 2] = a[4 * g + 2] * h[4 * g + 2] + du * bv.z;
          h[4 * g + 3] = a[4 * g + 3] * h[4 * g + 3] + du * bv.w;
          p[g] += cv.x * h[4 * g + 0];
          p[g] += cv.y * h[4 * g + 1];
          p[g] += cv.z * h[4 * g + 2];
          p[g] += cv.w * h[4 * g + 3];
        }
      } else {
        #pragma unroll
        for (int g = 0; g < 4; ++g) {
          float4 bv = sB4[t * 4 + g];
          float4 cv = sC4[t * 4 + g];
          float a0 = exp2f(dv * An[4 * g + 0]);
          float a1 = exp2f(dv * An[4 * g + 1]);
          float a2 = exp2f(dv * An[4 * g + 2]);
          float a3 = exp2f(dv * An[4 * g + 3]);
          h[4 * g + 0] = a0 * h[4 * g + 0] + du * bv.x;
          h[4 * g + 1] = a1 * h[4 * g + 1] + du * bv.y;
          h[4 * g + 2] = a2 * h[4 * g + 2] + du * bv.z;
          h[4 * g + 3] = a3 * h[4 * g + 3] + du * bv.w;
          p[g] += cv.x * h[4 * g + 0];
          p[g] += cv.y * h[4 * g + 1];
          p[g] += cv.z * h[4 * g + 2];
          p[g] += cv.w * h[4 * g + 3];
        }
      }
      float yv = Dd * uv + ((p[0] + p[1]) + (p[2] + p[3]));
      yA[ybase + rbase + i * rstep] = yv;
    }
  }
}

// ---------------- same-row combine 4 dirs + LayerNorm + sign(z) gate + output bilinear ----------------
// grid 1024: 16 rows/block.
__global__ __launch_bounds__(256) void k_ln_out(
    const float* __restrict__ yA, const uint32_t* __restrict__ pxin,
    const float* __restrict__ b_in, const float* __restrict__ s_in,
    const float* __restrict__ ln_w, const float* __restrict__ ln_b,
    const float* __restrict__ ws, const float* __restrict__ b_out,
    const float* __restrict__ s_out, float* __restrict__ out) {
  __shared__ float ty[16 * 193];
  __shared__ float ps[256];
  __shared__ float smu[16], srs[16];
  __shared__ float slw[DN], slb[DN];
  __shared__ uint32_t ybits[16 * 6];
  __shared__ uint32_t swo[96 * 6];
  __shared__ float sb[96], ssc[96];
  __shared__ uint32_t szw[DN * 3];
  __shared__ float szb[DN], szs[DN];
  __shared__ uint32_t spxt[16 * 3];
  int b = blockIdx.x >> 8;
  int l0 = (blockIdx.x & 255) << 4;
  if (threadIdx.x < DN) {
    slw[threadIdx.x] = ln_w[threadIdx.x];
    slb[threadIdx.x] = ln_b[threadIdx.x];
    szb[threadIdx.x] = b_in[DN + threadIdx.x];
    szs[threadIdx.x] = s_in[DN + threadIdx.x];
  }
  for (int i = threadIdx.x; i < 96 * 6; i += 256) swo[i] = ((const uint32_t*)(ws + OFF_WOUTB))[i];
  for (int i = threadIdx.x; i < DN * 3; i += 256) szw[i] = ((const uint32_t*)(ws + OFF_WBIB))[DN * 3 + i];
  if (threadIdx.x < 96) {
    sb[threadIdx.x] = b_out[threadIdx.x];
    ssc[threadIdx.x] = s_out[threadIdx.x];
  }
  if (threadIdx.x < 48) spxt[threadIdx.x] = pxin[(size_t)(b * LL + l0) * 3 + threadIdx.x];
  // scan_c stored every direction's y at its SPATIAL row -> same-row sum over k.
  const float* y0 = yA + (size_t)(b * 4 + 0) * (LL * DN) + (size_t)l0 * DN;
  const float* y1 = yA + (size_t)(b * 4 + 1) * (LL * DN) + (size_t)l0 * DN;
  const float* y2 = yA + (size_t)(b * 4 + 2) * (LL * DN) + (size_t)l0 * DN;
  const float* y3 = yA + (size_t)(b * 4 + 3) * (LL * DN) + (size_t)l0 * DN;
  for (int i = threadIdx.x; i < 16 * DN; i += 256) {
    int lc = i / DN, dd = i - lc * DN;
    size_t off = (size_t)lc * DN + dd;
    ty[lc * 193 + dd] = y0[off] + y1[off] + y2[off] + y3[off];
  }
  __syncthreads();
  int lc = threadIdx.x & 15, part = threadIdx.x >> 4;   // 16 parts x 12 d each
  float s = 0.f;
  for (int d = part * 12; d < part * 12 + 12; ++d) s += ty[lc * 193 + d];
  ps[threadIdx.x] = s;
  __syncthreads();
  if (threadIdx.x < 16) {
    float m = 0.f;
    #pragma unroll
    for (int p = 0; p < 16; ++p) m += ps[p * 16 + threadIdx.x];
    smu[threadIdx.x] = m / (float)DN;
  }
  __syncthreads();
  float mu = smu[lc];
  float q = 0.f;
  for (int d = part * 12; d < part * 12 + 12; ++d) {
    float v = ty[lc * 193 + d] - mu; q += v * v;
  }
  ps[threadIdx.x] = q;
  __syncthreads();
  if (threadIdx.x < 16) {
    float vv = 0.f;
    #pragma unroll
    for (int p = 0; p < 16; ++p) vv += ps[p * 16 + threadIdx.x];
    srs[threadIdx.x] = rsqrtf(vv / (float)DN + 1e-5f);
  }
  __syncthreads();
  if (threadIdx.x < 16 * 6) {
    int lc2 = threadIdx.x / 6, wd = threadIdx.x % 6;
    float mu2 = smu[lc2], rs2 = srs[lc2];
    uint32_t px0 = spxt[lc2 * 3 + 0], px1 = spxt[lc2 * 3 + 1], px2 = spxt[lc2 * 3 + 2];
    uint32_t wv = 0;
    #pragma unroll
    for (int i = 0; i < 32; ++i) {
      int dd = wd * 32 + i;
      float lnv = (ty[lc2 * 193 + dd] - mu2) * rs2 * slw[dd] + slb[dd];
      // gate: only the SIGN of ln * silu(z) matters, and sign(silu(z)) == sign(z)
      int P = (int)__popc(px0 ^ szw[dd * 3 + 0]) + (int)__popc(px1 ^ szw[dd * 3 + 1]) +
              (int)__popc(px2 ^ szw[dd * 3 + 2]);
      float zv = szb[dd] + szs[dd] * (float)(DM - 2 * P);
      wv |= ((lnv * zv > 0.f) ? 1u : 0u) << i;
    }
    ybits[lc2 * 6 + wd] = wv;
  }
  __syncthreads();
  float* op = out + (size_t)(b * LL + l0) * DM;
  for (int oi = threadIdx.x; oi < 16 * DM; oi += 256) {
    int pr = oi / DM, m = oi % DM;
    int P = 0;
    #pragma unroll
    for (int j = 0; j < 6; ++j) P += (int)__popc(ybits[pr * 6 + j] ^ swo[m * 6 + j]);
    op[(size_t)pr * DM + m] = sb[m] + ssc[m] * (float)(DN - 2 * P);
  }
}

extern "C" void kernel_launch(void* const* d_in, const int* in_sizes, int n_in,
                              void* d_out, int out_size, void* d_ws, size_t ws_size,
                              hipStream_t stream) {
  const float* x       = (const float*)d_in[0];
  const float* W_in    = (const float*)d_in[1];
  const float* b_in    = (const float*)d_in[2];
  const float* s_in    = (const float*)d_in[3];
  const float* move0_b = (const float*)d_in[4];
  const float* conv_W  = (const float*)d_in[5];
  const float* conv_b  = (const float*)d_in[6];
  const float* rp_b0   = (const float*)d_in[7];
  const float* prelu_a = (const float*)d_in[8];
  const float* rp_b1   = (const float*)d_in[9];
  const float* Wl      = (const float*)d_in[10];
  const float* bl      = (const float*)d_in[11];
  const float* sl      = (const float*)d_in[12];
  const float* Wd      = (const float*)d_in[13];
  const float* bd      = (const float*)d_in[14];
  const float* sd      = (const float*)d_in[15];
  const float* dt_bias = (const float*)d_in[16];
  const float* A_logs  = (const float*)d_in[17];
  const float* Ds      = (const float*)d_in[18];
  const float* ln_w    = (const float*)d_in[19];
  const float* ln_b    = (const float*)d_in[20];
  const float* W_out   = (const float*)d_in[21];
  const float* b_out   = (const float*)d_in[22];
  const float* s_out   = (const float*)d_in[23];
  float* ws  = (float*)d_ws;
  float* out = (float*)d_out;

  hipLaunchKernelGGL(k_prep, dim3(1616), dim3(64), 0, stream,
                     W_in, s_in, W_out, s_out, Wl, sl, Wd, sd, conv_W, ws);
  hipLaunchKernelGGL(k_bilin_in, dim3(1024), dim3(384), 0, stream,
                     x, b_in, s_in, move0_b, ws, ws + OFF_XP,
                     (uint32_t*)(ws + OFF_PXIN), (uint32_t*)(ws + OFF_XBP));
  hipLaunchKernelGGL(k_conv, dim3(1024), dim3(256), 0, stream,
                     (const uint32_t*)(ws + OFF_XBP), ws + OFF_XP,
                     (const uint32_t*)(ws + OFF_WCS), (const int*)(ws + OFF_WAUX),
                     ws + OFF_WSC, conv_b, rp_b0, prelu_a, rp_b1,
                     ws + OFF_XCONV);
  hipLaunchKernelGGL(k_bits_xpose, dim3(1536), dim3(256), 0, stream,
                     ws + OFF_XCONV, (uint32_t*)(ws + OFF_PXS), ws + OFF_XCT);
  hipLaunchKernelGGL(k_scan_a, dim3(2048), dim3(192), 0, stream,
                     ws + OFF_XCT, (const uint32_t*)(ws + OFF_PXS), ws, bl, sl,
                     bd, dt_bias, A_logs, ws + OFF_HEND, ws + OFF_SSUM);
  hipLaunchKernelGGL(k_scan_b, dim3(192), dim3(256), 0, stream,
                     A_logs, ws + OFF_SSUM, ws + OFF_HEND);
  hipLaunchKernelGGL(k_scan_c, dim3(2048), dim3(192), 0, stream,
                     ws + OFF_XCT, (const uint32_t*)(ws + OFF_PXS), ws, bl, sl,
                     bd, dt_bias, A_logs, Ds, ws + OFF_YA, ws + OFF_HEND);
  hipLaunchKernelGGL(k_ln_out, dim3(1024), dim3(256), 0, stream,
                     ws + OFF_YA, (const uint32_t*)(ws + OFF_PXIN), b_in, s_in,
                     ln_w, ln_b, ws, b_out, s_out, out);
}

// Round 14
// 277.253 us; speedup vs baseline: 1.1646x; 1.0833x over previous
//
#include <hip/hip_runtime.h>
#include <math.h>
#include <stdint.h>

// Problem constants
#define BB 4
#define HH 64
#define WW2 64
#define DM 96
#define DN 192
#define KK 4
#define NN 16
#define RR 6
#define LL 4096
#define RN 38   // R + 2N

#define LOG2E 1.4426950408889634f
#define LN2   0.6931471805599453f

// Workspace layout (4-byte word units). Peak = 23,293,200 words = 93.2 MB.
#define OFF_WDB      0           // u32[768] packed Wd sign bits + float[768] sd at +768
#define OFF_WCS      4608        // u32[192*56] packed conv weights
#define OFF_WAUX     15360       // int[192*8] conv border corrections
#define OFF_WSC      16896       // float[192] conv scale
#define OFF_WBIB     17088       // u32[384*3] packed W_in sign bits (rows 0..191 xp-half, 192..383 z-half)
#define OFF_WOUTB    18240       // u32[96*6] packed W_out sign bits
#define OFF_WLBB     18816       // u32[152*6] packed Wl sign bits
#define OFF_XBP      19728       // u32[4*6*4356] conv input bit planes (dead after k_conv)
#define OFF_PXS      19728       // u32[16*24576] packed sign(xs) flat — overwrites XBP, live thru scan_c
#define OFF_PXIN     412944     // u32[16384*3] input x sign bits (bilin_in -> ln_out)
#define OFF_XP       462096     // float[3145728] xp (B,Dn,L), dead after k_conv
#define OFF_XCONV    3607824    // float[3145728] conv out (B,Dn,L), dead after bits+xpose
#define OFF_XCT      6753552    // float[3145728] xconv t-major (B,L,Dn), live thru scan_c
#define OFF_HEND     462096     // float[128*49152] chunk h-ends / h0 (over dead XP+XCONV)
#define OFF_YA       9899280    // float[12582912] per-direction y (B,K,L,Dn), scan_c -> ln_out
#define OFF_SSUM     22482192   // float[128*3072] chunk delta sums
#define OFF_GE       22875408   // float[8*49152] group h-end summaries (scan_b1 -> b2)
#define OFF_GSG      23268624   // float[8*3072] group S sums

#define PLANE 4356   // 66*66
#define NCH 128      // 4096 / CHUNK
#define CHUNK 32

__device__ __forceinline__ float softplusf(float v) {
  return fmaxf(v, 0.f) + LN2 * log2f(1.f + exp2f(-fabsf(v) * LOG2E));
}
__device__ __forceinline__ float siluf(float v) {
  return v / (1.f + expf(-v));
}
__device__ __forceinline__ float waveAllSum(float s) {
  #pragma unroll
  for (int off = 32; off; off >>= 1) s += __shfl_xor(s, off, 64);
  return s;
}

// ---------------- prep: pack all sign weights + zero conv-plane borders ----------------
__global__ __launch_bounds__(64) void k_prep(
    const float* __restrict__ W_in, const float* __restrict__ s_in,
    const float* __restrict__ W_out, const float* __restrict__ s_out,
    const float* __restrict__ Wl, const float* __restrict__ sl,
    const float* __restrict__ Wd, const float* __restrict__ sd,
    const float* __restrict__ convW, float* __restrict__ ws) {
  __shared__ float srow[1728];
  int r = blockIdx.x, lane = threadIdx.x;
  if (r < 384) {
    const float* row = W_in + r * DM;
    float s = 0.f;
    for (int c = lane; c < DM; c += 64) s += row[c];
    s = waveAllSum(s);
    float mean = s / (float)DM;
    if (lane < 3) {
      uint32_t wv = 0;
      #pragma unroll
      for (int i = 0; i < 32; ++i) wv |= (row[lane * 32 + i] - mean > 0.f ? 1u : 0u) << i;
      ((uint32_t*)(ws + OFF_WBIB))[r * 3 + lane] = wv;
    }
  } else if (r < 480) {
    int m = r - 384;
    const float* row = W_out + m * DN;
    float s = 0.f;
    for (int c = lane; c < DN; c += 64) s += row[c];
    s = waveAllSum(s);
    float mean = s / (float)DN;
    if (lane < 6) {
      uint32_t wv = 0;
      #pragma unroll
      for (int i = 0; i < 32; ++i) wv |= (row[lane * 32 + i] - mean > 0.f ? 1u : 0u) << i;
      ((uint32_t*)(ws + OFF_WOUTB))[m * 6 + lane] = wv;
    }
  } else if (r < 632) {
    int idx = r - 480;
    const float* row = Wl + idx * DN;
    float s = 0.f;
    for (int c = lane; c < DN; c += 64) s += row[c];
    s = waveAllSum(s);
    float mean = s / (float)DN;
    if (lane < 6) {
      uint32_t wv = 0;
      #pragma unroll
      for (int i = 0; i < 32; ++i) wv |= (row[lane * 32 + i] - mean > 0.f ? 1u : 0u) << i;
      ((uint32_t*)(ws + OFF_WLBB))[idx * 6 + lane] = wv;
    }
  } else if (r < 1400) {
    int idx = r - 632;
    const float* row = Wd + idx * RR;
    float s = (lane < RR) ? row[lane] : 0.f;
    s = waveAllSum(s);
    float mean = s / (float)RR;
    unsigned long long mb = __ballot((lane < RR) && (row[lane] - mean > 0.f));
    if (lane == 0) {
      ((uint32_t*)(ws + OFF_WDB))[idx] = (uint32_t)mb & 0x3Fu;
      (ws + OFF_WDB)[768 + idx] = sd[idx];
    }
  } else if (r < 1592) {
    int o = r - 1400;
    const float* row = convW + o * 1728;
    float s = 0.f;
    for (int j = lane; j < 1728; j += 64) {
      float v = row[j];
      srow[j] = v;
      s += fabsf(v);
    }
    s = waveAllSum(s);
    __syncthreads();
    float sc = s / 1728.f;
    uint32_t* wb = (uint32_t*)(ws + OFF_WCS);
    int* aux = (int*)(ws + OFF_WAUX);
    float* scf = ws + OFF_WSC;
    uint32_t word = 0;
    if (lane < 54) {
      int cw = lane / 9, tap = lane % 9;
      #pragma unroll
      for (int i = 0; i < 32; ++i)
        word |= (srow[(cw * 32 + i) * 9 + tap] > 0.f ? 1u : 0u) << i;
      wb[o * 56 + lane] = word;
    } else if (lane < 56) {
      wb[o * 56 + lane] = 0u;
    }
    int pc = (lane < 54) ? 2 * (int)__popc(word) - 32 : 0;
    int tapid = lane % 9;
    int wst = 0;
    #pragma unroll
    for (int cw = 0; cw < 6; ++cw) wst += __shfl(pc, cw * 9 + tapid, 64);
    int w_t[9];
    #pragma unroll
    for (int t9 = 0; t9 < 9; ++t9) w_t[t9] = __shfl(wst, t9, 64);
    if (lane == 0) {
      aux[o * 8 + 0] = w_t[0] + w_t[3] + w_t[6];
      aux[o * 8 + 1] = w_t[2] + w_t[5] + w_t[8];
      aux[o * 8 + 2] = w_t[0] + w_t[1] + w_t[2];
      aux[o * 8 + 3] = w_t[6] + w_t[7] + w_t[8];
      aux[o * 8 + 4] = w_t[0];
      aux[o * 8 + 5] = w_t[2];
      aux[o * 8 + 6] = w_t[6];
      aux[o * 8 + 7] = w_t[8];
      scf[o] = sc;
    }
  } else {
    // zero the border of one conv bit-plane (24 planes)
    int p = r - 1592;
    uint32_t* plane = (uint32_t*)(ws + OFF_XBP) + (size_t)p * PLANE;
    for (int i = lane; i < 66; i += 64) {
      plane[i] = 0u;
      plane[65 * 66 + i] = 0u;
    }
    for (int i = lane; i < 64; i += 64) {
      plane[(i + 1) * 66] = 0u;
      plane[(i + 1) * 66 + 65] = 0u;
    }
  }
}

// ---------------- input bilinear (xp half only) + input sign-bit store + conv bit-pack ----------------
__global__ __launch_bounds__(384) void k_bilin_in(
    const float* __restrict__ x, const float* __restrict__ b_in,
    const float* __restrict__ s_in, const float* __restrict__ move0,
    const float* __restrict__ ws, float* __restrict__ xp,
    uint32_t* __restrict__ pxin, uint32_t* __restrict__ xb) {
  __shared__ uint32_t spx[16 * 3];
  __shared__ float sxz[192 * 17];
  __shared__ float smv[DN];
  int p0 = blockIdx.x * 16;
  if (threadIdx.x < 48) {
    int pix = threadIdx.x / 3, wd = threadIdx.x % 3;
    const float* base = x + (size_t)(p0 + pix) * DM + wd * 32;
    uint32_t wv = 0;
    #pragma unroll
    for (int i = 0; i < 32; ++i) wv |= (base[i] > 0.f ? 1u : 0u) << i;
    spx[pix * 3 + wd] = wv;
  }
  if (threadIdx.x < DN) smv[threadIdx.x] = move0[threadIdx.x];
  __syncthreads();
  int half = threadIdx.x / 192;
  int o = threadIdx.x - half * 192;
  uint32_t w0, w1, w2;
  {
    const uint32_t* wb = (const uint32_t*)(ws + OFF_WBIB) + o * 3;
    w0 = wb[0]; w1 = wb[1]; w2 = wb[2];
  }
  float bias = b_in[o], sc = s_in[o];
  #pragma unroll
  for (int pp = 0; pp < 8; ++pp) {
    int pix = half * 8 + pp;
    int P = (int)__popc(spx[pix * 3 + 0] ^ w0) + (int)__popc(spx[pix * 3 + 1] ^ w1) +
            (int)__popc(spx[pix * 3 + 2] ^ w2);
    sxz[o * 17 + pix] = bias + sc * (float)(DM - 2 * P);
  }
  __syncthreads();
  int b = p0 >> 12, l0 = p0 & 4095;
  for (int f = threadIdx.x; f < DN * 16; f += 384) {
    int od = f >> 4, pix = f & 15;
    xp[((size_t)(b * DN + od)) * LL + l0 + pix] = sxz[od * 17 + pix];
  }
  if (threadIdx.x < 48) {
    int pix = threadIdx.x / 3, wd = threadIdx.x % 3;
    pxin[(size_t)(p0 + pix) * 3 + wd] = spx[pix * 3 + wd];
  }
  if (threadIdx.x < 96) {
    int pix = threadIdx.x / 6, cw = threadIdx.x % 6;
    uint32_t wv = 0;
    #pragma unroll
    for (int i = 0; i < 32; ++i) {
      int dch = cw * 32 + i;
      wv |= ((sxz[dch * 17 + pix] + smv[dch] > 0.f) ? 1u : 0u) << i;
    }
    int l = l0 + pix, h = l >> 6, w = l & 63;
    uint32_t* plane = xb + (size_t)(b * 6 + cw) * PLANE;
    plane[(h + 1) * 66 + 1 + w] = wv;
  }
}

// ---------------- XNOR-popcount binary 3x3 conv + RPReLU + residual + SiLU ----------------
// grid 1024: b(4) x stripe(16) x og(4) x ocg(4); each block does 12 output channels.
__global__ __launch_bounds__(256) void k_conv(
    const uint32_t* __restrict__ xb, const float* __restrict__ xc,
    const uint32_t* __restrict__ wbits, const int* __restrict__ aux,
    const float* __restrict__ scf, const float* __restrict__ conv_b,
    const float* __restrict__ rp_b0, const float* __restrict__ prelu_a,
    const float* __restrict__ rp_b1, float* __restrict__ xconv) {
  int ocg = blockIdx.x & 3;
  int og = (blockIdx.x >> 2) & 3;
  int stripe = (blockIdx.x >> 4) & 15;
  int b = blockIdx.x >> 8;
  int w = threadIdx.x & 63, r = threadIdx.x >> 6;
  int h = stripe * 4 + r;
  int obase = og * 48 + ocg * 12;

  __shared__ uint32_t swb[12 * 56];
  __shared__ int saux[12 * 8];
  __shared__ float sconst[12 * 4];
  for (int i = threadIdx.x; i < 12 * 56; i += 256) swb[i] = wbits[obase * 56 + i];
  for (int i = threadIdx.x; i < 12 * 8; i += 256) saux[i] = aux[obase * 8 + i];
  if (threadIdx.x < 12) {
    int o = obase + threadIdx.x;
    sconst[threadIdx.x * 4 + 0] = scf[o];
    sconst[threadIdx.x * 4 + 1] = conv_b[o] + rp_b0[o];
    sconst[threadIdx.x * 4 + 2] = prelu_a[o];
    sconst[threadIdx.x * 4 + 3] = rp_b1[o];
  }

  uint32_t xw[6][9];
  const uint32_t* xpb = xb + (size_t)b * 6 * PLANE;
  #pragma unroll
  for (int cw = 0; cw < 6; ++cw) {
    const uint32_t* plane = xpb + cw * PLANE + (h + 1) * 66 + (w + 1);
    #pragma unroll
    for (int dy = 0; dy < 3; ++dy) {
      #pragma unroll
      for (int dx = 0; dx < 3; ++dx)
        xw[cw][dy * 3 + dx] = plane[(dy - 1) * 66 + (dx - 1)];
    }
  }
  bool isL = (w == 0), isR = (w == 63);
  bool isT = (h == 0), isB = (h == 63);
  const float* xcp = xc + ((size_t)(b * DN + obase)) * LL + h * 64 + w;
  float* xop = xconv + ((size_t)(b * DN + obase)) * LL + h * 64 + w;
  __syncthreads();

  #pragma unroll 1
  for (int oc = 0; oc < 12; ++oc) {
    const uint32_t* wp = &swb[oc * 56];
    int P = 0;
    #pragma unroll
    for (int cw = 0; cw < 6; ++cw) {
      int pp = 0;
      #pragma unroll
      for (int t = 0; t < 9; ++t) pp += (int)__popc(wp[cw * 9 + t] ^ xw[cw][t]);
      P += pp;
    }
    int corr = isL ? saux[oc * 8 + 0] : (isR ? saux[oc * 8 + 1] : 0);
    if (isT) {
      corr += saux[oc * 8 + 2];
      if (isL) corr -= saux[oc * 8 + 4];
      if (isR) corr -= saux[oc * 8 + 5];
    }
    if (isB) {
      corr += saux[oc * 8 + 3];
      if (isL) corr -= saux[oc * 8 + 6];
      if (isR) corr -= saux[oc * 8 + 7];
    }
    float acc = sconst[oc * 4 + 0] * (float)(1728 - 2 * P + corr);
    float t = acc + sconst[oc * 4 + 1];
    t = (t >= 0.f) ? t : sconst[oc * 4 + 2] * t;
    t += sconst[oc * 4 + 3] + *xcp;
    *xop = siluf(t);
    xcp += LL; xop += LL;
  }
}

// ---------------- fused: pack sign bits (blocks 0..767) + transpose to t-major (768..1535) ----------------
__global__ __launch_bounds__(256) void k_bits_xpose(const float* __restrict__ xconv,
                                                    uint32_t* __restrict__ pxs,
                                                    float* __restrict__ xct) {
  __shared__ float tile[64][65];
  if (blockIdx.x < 768) {
    int bd = blockIdx.x;
    int b = bd / DN, dch = bd - b * DN;
    const float* img = xconv + (size_t)bd * LL;
    for (int i = threadIdx.x; i < LL; i += 256)
      tile[i >> 6][i & 63] = img[i];
    __syncthreads();
    int lane = threadIdx.x & 63;
    #pragma unroll
    for (int k = 0; k < 4; ++k) {
      size_t wbase = ((size_t)((b * KK + k) * DN + dch)) * 128;
      for (int j = threadIdx.x; j < LL; j += 256) {
        float v;
        if (k == 0)      v = tile[j >> 6][j & 63];
        else if (k == 1) v = tile[j & 63][j >> 6];
        else if (k == 2) { int t2 = 4095 - j; v = tile[t2 >> 6][t2 & 63]; }
        else             { int t2 = 4095 - j; v = tile[t2 & 63][t2 >> 6]; }
        unsigned long long m = __ballot(v > 0.f);
        if (lane == 0)       pxs[wbase + (j >> 5)] = (uint32_t)m;
        else if (lane == 32) pxs[wbase + (j >> 5)] = (uint32_t)(m >> 32);
      }
    }
  } else {
    int idx = blockIdx.x - 768;
    int ts = idx & 63;
    int rest = idx >> 6;       // 0..11
    int dg = rest % 3;
    int b = rest / 3;
    int d0 = dg * 64, t0 = ts * 64;
    for (int i = threadIdx.x; i < 4096; i += 256) {
      int dd = i >> 6, tt = i & 63;
      tile[dd][tt] = xconv[((size_t)(b * DN + d0 + dd)) * LL + t0 + tt];
    }
    __syncthreads();
    for (int i = threadIdx.x; i < 4096; i += 256) {
      int tt = i >> 6, dd = i & 63;
      xct[((size_t)(b * LL + t0 + tt)) * DN + d0 + dd] = tile[dd][tt];
    }
  }
}

// power ladder: a[n] = r^(n+1), 14 mults, depth 4
__device__ __forceinline__ void rpowers(float r, float* a) {
  float r2 = r * r, r3 = r2 * r, r4 = r2 * r2, r8 = r4 * r4;
  a[0] = r;       a[1] = r2;      a[2] = r3;      a[3] = r4;
  a[4] = r4 * r;  a[5] = r4 * r2; a[6] = r4 * r3; a[7] = r8;
  a[8] = r8 * r;  a[9] = r8 * r2; a[10] = r8 * r3; a[11] = r8 * r4;
  a[12] = r8 * a[4]; a[13] = r8 * a[5]; a[14] = r8 * a[6]; a[15] = r8 * r8;
}

// row step (in floats) per unit t, valid within any 8-aligned seg (no low-6-bit carry)
__device__ __forceinline__ int rowstep(int k) {
  return (k == 0) ? DN : (k == 1) ? 64 * DN : (k == 2) ? -DN : -64 * DN;
}
__device__ __forceinline__ int rowbase(int k, int tb) {
  int r0 = (k >= 2) ? (4095 - tb) : tb;
  if (k & 1) r0 = ((r0 & 63) << 6) | (r0 >> 6);
  return r0 * DN;
}

// ---------------- scan pass A: recurrence ONLY -> h-ends + Ssum (no y, no C) ----------------
// grid = 128 chunks x 16 bk; 192 threads (one per d).
__global__ __launch_bounds__(192) void k_scan_a(
    const float* __restrict__ xct, const uint32_t* __restrict__ pxs,
    const float* __restrict__ ws, const float* __restrict__ bl,
    const float* __restrict__ sl, const float* __restrict__ bd,
    const float* __restrict__ dt_bias, const float* __restrict__ A_logs,
    float* __restrict__ hend, float* __restrict__ Ssum) {
  int c = blockIdx.x & (NCH - 1);
  int bk = blockIdx.x >> 7;
  int k = bk & 3, b = bk >> 2;
  int d = threadIdx.x;
  int t0 = c << 5;
  __shared__ uint32_t sdtm[CHUNK];
  __shared__ uint32_t spxr[CHUNK * 6];
  __shared__ uint32_t swl[RN * 6];
  __shared__ float sblv[RN], sslv[RN];
  __shared__ float4 sB4[CHUNK * 4];
  __shared__ float sDV[7 * 192], sR[7 * 192];
  float* sBf = (float*)sB4;
  const uint32_t* ppx = pxs + (size_t)bk * 24576;
  spxr[d] = ppx[t0 * 6 + d];                       // 192 words = 32 rows x 6
  for (int i = d; i < RN * 6; i += 192) swl[i] = ((const uint32_t*)(ws + OFF_WLBB))[k * RN * 6 + i];
  if (d < RN) {
    sblv[d] = bl[k * RN + d];
    sslv[d] = sl[k * RN + d];
  }
  __syncthreads();
  // dt sign masks via raw-reshape mapping f = t*6+r -> row f>>12, col f&4095
  if (d < CHUNK) {
    uint32_t m = 0;
    int fbase = (t0 + d) * 6;
    #pragma unroll
    for (int r = 0; r < 6; ++r) {
      int f = fbase + r;
      int o = f >> 12, l = f & 4095;
      const uint32_t* prow = ppx + l * 6;
      int P = 0;
      #pragma unroll
      for (int j = 0; j < 6; ++j) P += (int)__popc(prow[j] ^ swl[o * 6 + j]);
      float val = sblv[o] + sslv[o] * (float)(DN - 2 * P);
      m |= (val > 0.f ? 1u : 0u) << r;
    }
    sdtm[d] = m;
  }
  // B values only: rows RR..RR+15
  for (int i = d; i < CHUNK * 16; i += 192) {
    int t = i >> 4, n = i & 15;
    int o = RR + n;
    int P = 0;
    #pragma unroll
    for (int j = 0; j < 6; ++j) P += (int)__popc(spxr[t * 6 + j] ^ swl[o * 6 + j]);
    sBf[t * 16 + n] = sblv[o] + sslv[o] * (float)(DN - 2 * P);
  }
  uint32_t w6 = ((const uint32_t*)(ws + OFF_WDB))[k * DN + d];
  float sdvv = (ws + OFF_WDB)[768 + k * DN + d];
  float biasd = bd[k * DN + d] + dt_bias[k * DN + d];
  #pragma unroll
  for (int pc = 0; pc < 7; ++pc) {
    float dv = softplusf(biasd + sdvv * (float)(RR - 2 * pc));
    sDV[pc * 192 + d] = dv;
    sR[pc * 192 + d] = exp2f(-dv * LOG2E);
  }
  float Araw[16];
  bool fok = true;
  {
    const float* ap = A_logs + (k * DN + d) * NN;
    #pragma unroll
    for (int n = 0; n < NN; ++n) {
      Araw[n] = -expf(ap[n]);
      fok = fok && (fabsf(Araw[n] + (float)(n + 1)) < 1e-3f);
    }
  }
  bool fastpath = (__ballot(fok) == ~0ull);
  float An[16];
  if (!fastpath) {
    #pragma unroll
    for (int n = 0; n < NN; ++n) An[n] = Araw[n] * LOG2E;
  }
  float h[16];
  #pragma unroll
  for (int n = 0; n < NN; ++n) h[n] = 0.f;
  float S = 0.f;
  int ubase = b * (LL * DN) + d;
  int rstep = rowstep(k);
  __syncthreads();
  #pragma unroll 1
  for (int seg = 0; seg < 4; ++seg) {
    int rbase = rowbase(k, t0 + seg * 8);
    float uu[8];
    #pragma unroll
    for (int i = 0; i < 8; ++i) uu[i] = xct[ubase + rbase + i * rstep];
    #pragma unroll
    for (int i = 0; i < 8; ++i) {
      int t = seg * 8 + i;
      float uv = uu[i];
      int pc = (int)__popc(sdtm[t] ^ w6);
      float dv = sDV[pc * 192 + d];
      S += dv;
      float du = dv * uv;
      if (fastpath) {
        float rv = sR[pc * 192 + d];
        float a[16];
        rpowers(rv, a);
        #pragma unroll
        for (int g = 0; g < 4; ++g) {
          float4 bv = sB4[t * 4 + g];
          h[4 * g + 0] = a[4 * g + 0] * h[4 * g + 0] + du * bv.x;
          h[4 * g + 1] = a[4 * g + 1] * h[4 * g + 1] + du * bv.y;
          h[4 * g + 2] = a[4 * g + 2] * h[4 * g + 2] + du * bv.z;
          h[4 * g + 3] = a[4 * g + 3] * h[4 * g + 3] + du * bv.w;
        }
      } else {
        #pragma unroll
        for (int g = 0; g < 4; ++g) {
          float4 bv = sB4[t * 4 + g];
          float a0 = exp2f(dv * An[4 * g + 0]);
          float a1 = exp2f(dv * An[4 * g + 1]);
          float a2 = exp2f(dv * An[4 * g + 2]);
          float a3 = exp2f(dv * An[4 * g + 3]);
          h[4 * g + 0] = a0 * h[4 * g + 0] + du * bv.x;
          h[4 * g + 1] = a1 * h[4 * g + 1] + du * bv.y;
          h[4 * g + 2] = a2 * h[4 * g + 2] + du * bv.z;
          h[4 * g + 3] = a3 * h[4 * g + 3] + du * bv.w;
        }
      }
    }
  }
  float* hp = hend + (size_t)c * 49152 + (size_t)(bk * DN + d) * 16;
  #pragma unroll
  for (int n = 0; n < NN; n += 4)
    *(float4*)(hp + n) = make_float4(h[n], h[n + 1], h[n + 2], h[n + 3]);
  Ssum[c * 3072 + bk * DN + d] = S;
}

// ---------------- scan pass B1: per-group (16 chunks) local prefix + group summary ----------------
// grid 1536 = 8 groups x 192; in-place: hend[c] <- exclusive local prefix.
__global__ __launch_bounds__(256) void k_scan_b1(
    const float* __restrict__ A_logs, const float* __restrict__ Ssum,
    float* __restrict__ hend, float* __restrict__ gE, float* __restrict__ gSG) {
  int g = blockIdx.x / 192;
  int blk = blockIdx.x - g * 192;
  int tid = blk * 256 + threadIdx.x;
  int bkd = tid >> 4, n = tid & 15;
  int bk = bkd / DN, d = bkd - bk * DN;
  int k = bk & 3;
  float An2 = -expf(A_logs[(k * DN + d) * NN + n]) * LOG2E;
  int c0 = g * 16;
  float E = 0.f, SG = 0.f;
  float Sc = Ssum[c0 * 3072 + bkd];
  float he = hend[(size_t)c0 * 49152 + tid];
  #pragma unroll 1
  for (int j = 0; j < 16; ++j) {
    int c = c0 + j;
    float Sn = 0.f, hn = 0.f;
    if (j < 15) {
      Sn = Ssum[(c + 1) * 3072 + bkd];
      hn = hend[(size_t)(c + 1) * 49152 + tid];
    }
    hend[(size_t)c * 49152 + tid] = E;
    E = exp2f(An2 * Sc) * E + he;
    SG += Sc;
    Sc = Sn; he = hn;
  }
  gE[(size_t)g * 49152 + tid] = E;
  if (n == 0) gSG[g * 3072 + bkd] = SG;
}

// ---------------- scan pass B2: compose group summaries, apply to local prefixes ----------------
// grid 1536 = 8 groups x 192; each block composes its <=7 predecessor groups in registers.
__global__ __launch_bounds__(256) void k_scan_b2(
    const float* __restrict__ A_logs, const float* __restrict__ Ssum,
    float* __restrict__ hend, const float* __restrict__ gE,
    const float* __restrict__ gSG) {
  int g = blockIdx.x / 192;
  if (g == 0) return;                         // H_0 = 0, nothing to add
  int blk = blockIdx.x - g * 192;
  int tid = blk * 256 + threadIdx.x;
  int bkd = tid >> 4, n = tid & 15;
  int bk = bkd / DN, d = bkd - bk * DN;
  int k = bk & 3;
  float An2 = -expf(A_logs[(k * DN + d) * NN + n]) * LOG2E;
  float H = 0.f;
  #pragma unroll 1
  for (int j = 0; j < g; ++j) {               // g uniform per block -> no divergence
    float Aj = exp2f(An2 * gSG[j * 3072 + bkd]);
    H = Aj * H + gE[(size_t)j * 49152 + tid];
  }
  int c0 = g * 16;
  float Spre = 0.f;
  #pragma unroll 1
  for (int j = 0; j < 16; ++j) {
    int c = c0 + j;
    hend[(size_t)c * 49152 + tid] += exp2f(An2 * Spre) * H;
    Spre += Ssum[c * 3072 + bkd];
  }
}

// ---------------- scan pass C: FULL scan from h0, single y write (no RMW) ----------------
// h initialized from h0buf (hend after scan_b); yv via 4-partial tree (reassociation OK).
// Stores y at the SPATIAL row -> same-row sum in ln_out.
__global__ __launch_bounds__(192) void k_scan_c(
    const float* __restrict__ xct, const uint32_t* __restrict__ pxs,
    const float* __restrict__ ws, const float* __restrict__ bl,
    const float* __restrict__ sl, const float* __restrict__ bd,
    const float* __restrict__ dt_bias, const float* __restrict__ A_logs,
    const float* __restrict__ Ds, float* __restrict__ yA,
    const float* __restrict__ h0buf) {
  int c = blockIdx.x & (NCH - 1);
  int bk = blockIdx.x >> 7;
  int k = bk & 3, b = bk >> 2;
  int d = threadIdx.x;
  int t0 = c << 5;
  __shared__ uint32_t sdtm[CHUNK];
  __shared__ uint32_t spxr[CHUNK * 6];
  __shared__ uint32_t swl[RN * 6];
  __shared__ float sblv[RN], sslv[RN];
  __shared__ float4 sB4[CHUNK * 4];
  __shared__ float4 sC4[CHUNK * 4];
  __shared__ float sDV[7 * 192], sR[7 * 192];
  float* sBf = (float*)sB4;
  float* sCf = (float*)sC4;
  const uint32_t* ppx = pxs + (size_t)bk * 24576;
  spxr[d] = ppx[t0 * 6 + d];
  for (int i = d; i < RN * 6; i += 192) swl[i] = ((const uint32_t*)(ws + OFF_WLBB))[k * RN * 6 + i];
  if (d < RN) {
    sblv[d] = bl[k * RN + d];
    sslv[d] = sl[k * RN + d];
  }
  __syncthreads();
  if (d < CHUNK) {
    uint32_t m = 0;
    int fbase = (t0 + d) * 6;
    #pragma unroll
    for (int r = 0; r < 6; ++r) {
      int f = fbase + r;
      int o = f >> 12, l = f & 4095;
      const uint32_t* prow = ppx + l * 6;
      int P = 0;
      #pragma unroll
      for (int j = 0; j < 6; ++j) P += (int)__popc(prow[j] ^ swl[o * 6 + j]);
      float val = sblv[o] + sslv[o] * (float)(DN - 2 * P);
      m |= (val > 0.f ? 1u : 0u) << r;
    }
    sdtm[d] = m;
  }
  // B and C values: rows RR..RR+31
  for (int i = d; i < CHUNK * 32; i += 192) {
    int t = i >> 5, nn = i & 31;
    int o = RR + nn;
    int P = 0;
    #pragma unroll
    for (int j = 0; j < 6; ++j) P += (int)__popc(spxr[t * 6 + j] ^ swl[o * 6 + j]);
    float val = sblv[o] + sslv[o] * (float)(DN - 2 * P);
    if (nn < 16) sBf[t * 16 + nn] = val;
    else         sCf[t * 16 + (nn - 16)] = val;
  }
  uint32_t w6 = ((const uint32_t*)(ws + OFF_WDB))[k * DN + d];
  float sdvv = (ws + OFF_WDB)[768 + k * DN + d];
  float biasd = bd[k * DN + d] + dt_bias[k * DN + d];
  float Dd = Ds[k * DN + d];
  #pragma unroll
  for (int pc = 0; pc < 7; ++pc) {
    float dv = softplusf(biasd + sdvv * (float)(RR - 2 * pc));
    sDV[pc * 192 + d] = dv;
    sR[pc * 192 + d] = exp2f(-dv * LOG2E);
  }
  float Araw[16];
  bool fok = true;
  {
    const float* ap = A_logs + (k * DN + d) * NN;
    #pragma unroll
    for (int n = 0; n < NN; ++n) {
      Araw[n] = -expf(ap[n]);
      fok = fok && (fabsf(Araw[n] + (float)(n + 1)) < 1e-3f);
    }
  }
  bool fastpath = (__ballot(fok) == ~0ull);
  float An[16];
  if (!fastpath) {
    #pragma unroll
    for (int n = 0; n < NN; ++n) An[n] = Araw[n] * LOG2E;
  }
  // h0 from scan_b output (zeros for c==0)
  float h[16];
  {
    const float* hp = h0buf + (size_t)c * 49152 + (size_t)(bk * DN + d) * 16;
    #pragma unroll
    for (int n = 0; n < NN; n += 4) {
      float4 v = *(const float4*)(hp + n);
      h[n] = v.x; h[n + 1] = v.y; h[n + 2] = v.z; h[n + 3] = v.w;
    }
  }
  int ubase = b * (LL * DN) + d;
  int ybase = bk * (LL * DN) + d;
  int rstep = rowstep(k);
  __syncthreads();
  #pragma unroll 1
  for (int seg = 0; seg < 4; ++seg) {
    int rbase = rowbase(k, t0 + seg * 8);
    float uu[8];
    #pragma unroll
    for (int i = 0; i < 8; ++i) uu[i] = xct[ubase + rbase + i * rstep];
    #pragma unroll
    for (int i = 0; i < 8; ++i) {
      int t = seg * 8 + i;
      float uv = uu[i];
      int pc = (int)__popc(sdtm[t] ^ w6);
      float dv = sDV[pc * 192 + d];
      float du = dv * uv;
      float p[4];
      #pragma unroll
      for (int g = 0; g < 4; ++g) p[g] = 0.f;
      if (fastpath) {
        float rv = sR[pc * 192 + d];
        float a[16];
        rpowers(rv, a);
        #pragma unroll
        for (int g = 0; g < 4; ++g) {
          float4 bv = sB4[t * 4 + g];
          float4 cv = sC4[t * 4 + g];
          h[4 * g + 0] = a[4 * g + 0] * h[4 * g + 0] + du * bv.x;
          h[4 * g + 1] = a[4 * g + 1] * h[4 * g + 1] + du * bv.y;
          h[4 * g + 2] = a[4 * g + 2] * h[4 * g + 2] + du * bv.z;
          h[4 * g + 3] = a[4 * g + 3] * h[4 * g + 3] + du * bv.w;
          p[g] += cv.x * h[4 * g + 0];
          p[g] += cv.y * h[4 * g + 1];
          p[g] += cv.z * h[4 * g + 2];
          p[g] += cv.w * h[4 * g + 3];
        }
      } else {
        #pragma unroll
        for (int g = 0; g < 4; ++g) {
          float4 bv = sB4[t * 4 + g];
          float4 cv = sC4[t * 4 + g];
          float a0 = exp2f(dv * An[4 * g + 0]);
          float a1 = exp2f(dv * An[4 * g + 1]);
          float a2 = exp2f(dv * An[4 * g + 2]);
          float a3 = exp2f(dv * An[4 * g + 3]);
          h[4 * g + 0] = a0 * h[4 * g + 0] + du * bv.x;
          h[4 * g + 1] = a1 * h[4 * g + 1] + du * bv.y;
          h[4 * g + 2] = a2 * h[4 * g + 2] + du * bv.z;
          h[4 * g + 3] = a3 * h[4 * g + 3] + du * bv.w;
          p[g] += cv.x * h[4 * g + 0];
          p[g] += cv.y * h[4 * g + 1];
          p[g] += cv.z * h[4 * g + 2];
          p[g] += cv.w * h[4 * g + 3];
        }
      }
      float yv = Dd * uv + ((p[0] + p[1]) + (p[2] + p[3]));
      yA[ybase + rbase + i * rstep] = yv;
    }
  }
}

// ---------------- same-row combine 4 dirs + LayerNorm + sign(z) gate + output bilinear ----------------
// grid 1024: 16 rows/block.
__global__ __launch_bounds__(256) void k_ln_out(
    const float* __restrict__ yA, const uint32_t* __restrict__ pxin,
    const float* __restrict__ b_in, const float* __restrict__ s_in,
    const float* __restrict__ ln_w, const float* __restrict__ ln_b,
    const float* __restrict__ ws, const float* __restrict__ b_out,
    const float* __restrict__ s_out, float* __restrict__ out) {
  __shared__ float ty[16 * 193];
  __shared__ float ps[256];
  __shared__ float smu[16], srs[16];
  __shared__ float slw[DN], slb[DN];
  __shared__ uint32_t ybits[16 * 6];
  __shared__ uint32_t swo[96 * 6];
  __shared__ float sb[96], ssc[96];
  __shared__ uint32_t szw[DN * 3];
  __shared__ float szb[DN], szs[DN];
  __shared__ uint32_t spxt[16 * 3];
  int b = blockIdx.x >> 8;
  int l0 = (blockIdx.x & 255) << 4;
  if (threadIdx.x < DN) {
    slw[threadIdx.x] = ln_w[threadIdx.x];
    slb[threadIdx.x] = ln_b[threadIdx.x];
    szb[threadIdx.x] = b_in[DN + threadIdx.x];
    szs[threadIdx.x] = s_in[DN + threadIdx.x];
  }
  for (int i = threadIdx.x; i < 96 * 6; i += 256) swo[i] = ((const uint32_t*)(ws + OFF_WOUTB))[i];
  for (int i = threadIdx.x; i < DN * 3; i += 256) szw[i] = ((const uint32_t*)(ws + OFF_WBIB))[DN * 3 + i];
  if (threadIdx.x < 96) {
    sb[threadIdx.x] = b_out[threadIdx.x];
    ssc[threadIdx.x] = s_out[threadIdx.x];
  }
  if (threadIdx.x < 48) spxt[threadIdx.x] = pxin[(size_t)(b * LL + l0) * 3 + threadIdx.x];
  // scan_c stored every direction's y at its SPATIAL row -> same-row sum over k.
  const float* y0 = yA + (size_t)(b * 4 + 0) * (LL * DN) + (size_t)l0 * DN;
  const float* y1 = yA + (size_t)(b * 4 + 1) * (LL * DN) + (size_t)l0 * DN;
  const float* y2 = yA + (size_t)(b * 4 + 2) * (LL * DN) + (size_t)l0 * DN;
  const float* y3 = yA + (size_t)(b * 4 + 3) * (LL * DN) + (size_t)l0 * DN;
  for (int i = threadIdx.x; i < 16 * DN; i += 256) {
    int lc = i / DN, dd = i - lc * DN;
    size_t off = (size_t)lc * DN + dd;
    ty[lc * 193 + dd] = y0[off] + y1[off] + y2[off] + y3[off];
  }
  __syncthreads();
  int lc = threadIdx.x & 15, part = threadIdx.x >> 4;   // 16 parts x 12 d each
  float s = 0.f;
  for (int d = part * 12; d < part * 12 + 12; ++d) s += ty[lc * 193 + d];
  ps[threadIdx.x] = s;
  __syncthreads();
  if (threadIdx.x < 16) {
    float m = 0.f;
    #pragma unroll
    for (int p = 0; p < 16; ++p) m += ps[p * 16 + threadIdx.x];
    smu[threadIdx.x] = m / (float)DN;
  }
  __syncthreads();
  float mu = smu[lc];
  float q = 0.f;
  for (int d = part * 12; d < part * 12 + 12; ++d) {
    float v = ty[lc * 193 + d] - mu; q += v * v;
  }
  ps[threadIdx.x] = q;
  __syncthreads();
  if (threadIdx.x < 16) {
    float vv = 0.f;
    #pragma unroll
    for (int p = 0; p < 16; ++p) vv += ps[p * 16 + threadIdx.x];
    srs[threadIdx.x] = rsqrtf(vv / (float)DN + 1e-5f);
  }
  __syncthreads();
  if (threadIdx.x < 16 * 6) {
    int lc2 = threadIdx.x / 6, wd = threadIdx.x % 6;
    float mu2 = smu[lc2], rs2 = srs[lc2];
    uint32_t px0 = spxt[lc2 * 3 + 0], px1 = spxt[lc2 * 3 + 1], px2 = spxt[lc2 * 3 + 2];
    uint32_t wv = 0;
    #pragma unroll
    for (int i = 0; i < 32; ++i) {
      int dd = wd * 32 + i;
      float lnv = (ty[lc2 * 193 + dd] - mu2) * rs2 * slw[dd] + slb[dd];
      // gate: only the SIGN of ln * silu(z) matters, and sign(silu(z)) == sign(z)
      int P = (int)__popc(px0 ^ szw[dd * 3 + 0]) + (int)__popc(px1 ^ szw[dd * 3 + 1]) +
              (int)__popc(px2 ^ szw[dd * 3 + 2]);
      float zv = szb[dd] + szs[dd] * (float)(DM - 2 * P);
      wv |= ((lnv * zv > 0.f) ? 1u : 0u) << i;
    }
    ybits[lc2 * 6 + wd] = wv;
  }
  __syncthreads();
  float* op = out + (size_t)(b * LL + l0) * DM;
  for (int oi = threadIdx.x; oi < 16 * DM; oi += 256) {
    int pr = oi / DM, m = oi % DM;
    int P = 0;
    #pragma unroll
    for (int j = 0; j < 6; ++j) P += (int)__popc(ybits[pr * 6 + j] ^ swo[m * 6 + j]);
    op[(size_t)pr * DM + m] = sb[m] + ssc[m] * (float)(DN - 2 * P);
  }
}

extern "C" void kernel_launch(void* const* d_in, const int* in_sizes, int n_in,
                              void* d_out, int out_size, void* d_ws, size_t ws_size,
                              hipStream_t stream) {
  const float* x       = (const float*)d_in[0];
  const float* W_in    = (const float*)d_in[1];
  const float* b_in    = (const float*)d_in[2];
  const float* s_in    = (const float*)d_in[3];
  const float* move0_b = (const float*)d_in[4];
  const float* conv_W  = (const float*)d_in[5];
  const float* conv_b  = (const float*)d_in[6];
  const float* rp_b0   = (const float*)d_in[7];
  const float* prelu_a = (const float*)d_in[8];
  const float* rp_b1   = (const float*)d_in[9];
  const float* Wl      = (const float*)d_in[10];
  const float* bl      = (const float*)d_in[11];
  const float* sl      = (const float*)d_in[12];
  const float* Wd      = (const float*)d_in[13];
  const float* bd      = (const float*)d_in[14];
  const float* sd      = (const float*)d_in[15];
  const float* dt_bias = (const float*)d_in[16];
  const float* A_logs  = (const float*)d_in[17];
  const float* Ds      = (const float*)d_in[18];
  const float* ln_w    = (const float*)d_in[19];
  const float* ln_b    = (const float*)d_in[20];
  const float* W_out   = (const float*)d_in[21];
  const float* b_out   = (const float*)d_in[22];
  const float* s_out   = (const float*)d_in[23];
  float* ws  = (float*)d_ws;
  float* out = (float*)d_out;

  hipLaunchKernelGGL(k_prep, dim3(1616), dim3(64), 0, stream,
                     W_in, s_in, W_out, s_out, Wl, sl, Wd, sd, conv_W, ws);
  hipLaunchKernelGGL(k_bilin_in, dim3(1024), dim3(384), 0, stream,
                     x, b_in, s_in, move0_b, ws, ws + OFF_XP,
                     (uint32_t*)(ws + OFF_PXIN), (uint32_t*)(ws + OFF_XBP));
  hipLaunchKernelGGL(k_conv, dim3(1024), dim3(256), 0, stream,
                     (const uint32_t*)(ws + OFF_XBP), ws + OFF_XP,
                     (const uint32_t*)(ws + OFF_WCS), (const int*)(ws + OFF_WAUX),
                     ws + OFF_WSC, conv_b, rp_b0, prelu_a, rp_b1,
                     ws + OFF_XCONV);
  hipLaunchKernelGGL(k_bits_xpose, dim3(1536), dim3(256), 0, stream,
                     ws + OFF_XCONV, (uint32_t*)(ws + OFF_PXS), ws + OFF_XCT);
  hipLaunchKernelGGL(k_scan_a, dim3(2048), dim3(192), 0, stream,
                     ws + OFF_XCT, (const uint32_t*)(ws + OFF_PXS), ws, bl, sl,
                     bd, dt_bias, A_logs, ws + OFF_HEND, ws + OFF_SSUM);
  hipLaunchKernelGGL(k_scan_b1, dim3(1536), dim3(256), 0, stream,
                     A_logs, ws + OFF_SSUM, ws + OFF_HEND, ws + OFF_GE, ws + OFF_GSG);
  hipLaunchKernelGGL(k_scan_b2, dim3(1536), dim3(256), 0, stream,
                     A_logs, ws + OFF_SSUM, ws + OFF_HEND, ws + OFF_GE, ws + OFF_GSG);
  hipLaunchKernelGGL(k_scan_c, dim3(2048), dim3(192), 0, stream,
                     ws + OFF_XCT, (const uint32_t*)(ws + OFF_PXS), ws, bl, sl,
                     bd, dt_bias, A_logs, Ds, ws + OFF_YA, ws + OFF_HEND);
  hipLaunchKernelGGL(k_ln_out, dim3(1024), dim3(256), 0, stream,
                     ws + OFF_YA, (const uint32_t*)(ws + OFF_PXIN), b_in, s_in,
                     ln_w, ln_b, ws, b_out, s_out, out);
}